// Round 4
// baseline (354.404 us; speedup 1.0000x reference)
//
#include <hip/hip_runtime.h>
#include <hip/hip_bf16.h>

#define B_    8
#define S_    32
#define H_    2048
#define NH_   16
#define NKV_  2
#define HD_   128
#define KV_   8192
#define G_    8
#define M_    256      /* B*S */
#define NQKV  2560     /* fused proj N: 2048 q | 256 k | 256 v */
#define NSP   32       /* kv splits */
#define KT_   64       /* kv subtile */
#define NT_   4        /* subtiles per block = KV_/NSP/KT_ */
#define SCALE_ 0.08838834764831845f

typedef __bf16 bf16x8 __attribute__((ext_vector_type(8)));
typedef float  f32x4  __attribute__((ext_vector_type(4)));
typedef float  f32x16 __attribute__((ext_vector_type(16)));

__device__ __forceinline__ unsigned short f2b(float f){
  unsigned u = __float_as_uint(f);
  u = u + 0x7FFFu + ((u>>16)&1u);           // RNE f32->bf16
  return (unsigned short)(u>>16);
}
__device__ __forceinline__ float b2f(unsigned short h){
  return __uint_as_float(((unsigned)h)<<16);
}
__device__ __forceinline__ unsigned pk2(float a, float b){
  return (unsigned)f2b(a) | ((unsigned)f2b(b)<<16);
}
__device__ __forceinline__ bf16x8 ld_frag(const unsigned short* p){
  union { uint4 u; bf16x8 b; } cv;
  cv.u = *(const uint4*)p;
  return cv.b;
}
__device__ __forceinline__ f32x4 mf(bf16x8 a, bf16x8 b, f32x4 c){
  return __builtin_amdgcn_mfma_f32_16x16x32_bf16(a, b, c, 0, 0, 0);
}
__device__ __forceinline__ f32x16 mf32(bf16x8 a, bf16x8 b, f32x16 c){
  return __builtin_amdgcn_mfma_f32_32x32x16_bf16(a, b, c, 0, 0, 0);
}
// K tile swizzle: 64 rows x 128 cols (shorts), 16B-group XOR
__device__ __forceinline__ int swiK(int row, int col){
  return row*128 + (col ^ ((((row)&15) ^ ((row>>1)&8)) << 3));
}
// Vt tile swizzle: 128 rows x 64 cols (shorts)
__device__ __forceinline__ int swiV(int row, int col){
  return row*64 + (col ^ (((row)&7) << 3));
}

// ---------------- K0: hidden_states f32 -> bf16 ----------------
__global__ __launch_bounds__(256) void k_cvt(const float* __restrict__ x,
                                             unsigned short* __restrict__ y){
  const int i = (blockIdx.x*256 + threadIdx.x)*4;
  const float4 v = *(const float4*)(x + i);
  ushort4 o; o.x=f2b(v.x); o.y=f2b(v.y); o.z=f2b(v.z); o.w=f2b(v.w);
  *(ushort4*)(y + i) = o;
}

// ---------------- K1: fused QKV projection GEMM (bf16 MFMA) ----------------
__global__ __launch_bounds__(256) void k_gemm_qkv(
    const unsigned short* __restrict__ A,
    const float* __restrict__ qw, const float* __restrict__ kw, const float* __restrict__ vw,
    const float* __restrict__ qbv, const float* __restrict__ kbv, const float* __restrict__ vbv,
    float* __restrict__ out)
{
  __shared__ unsigned short As[64][56];
  __shared__ unsigned short Bs[64][56];
  const int n0 = blockIdx.x*64, m0 = blockIdx.y*64;
  const float* W; const float* bias; int ldw, wc0;
  if(n0 < 2048)      { W=qw; bias=qbv; ldw=2048; wc0=n0; }
  else if(n0 < 2304) { W=kw; bias=kbv; ldw=256;  wc0=n0-2048; }
  else               { W=vw; bias=vbv; ldw=256;  wc0=n0-2304; }
  const int t = threadIdx.x, lane = t&63, wid = t>>6;
  const int wr = wid>>1, wc = wid&1, l15 = lane&15, lq = lane>>4;
  const int ar = t>>2,  ac = (t&3)*8;
  const int bk = t>>5,  bn = (t&31)*2;
  f32x4 acc[2][2] = {};
  for(int k0 = 0; k0 < 2048; k0 += 32){
    __syncthreads();
    *(uint4*)(&As[ar][ac]) = *(const uint4*)(A + (m0+ar)*2048 + k0 + ac);
    #pragma unroll
    for(int p=0;p<4;p++){
      const int kk = bk + p*8;
      const float2 wv = *(const float2*)(W + (long)(k0+kk)*ldw + wc0 + bn);
      Bs[bn  ][kk] = f2b(wv.x);
      Bs[bn+1][kk] = f2b(wv.y);
    }
    __syncthreads();
    const bf16x8 a0 = ld_frag(&As[wr*32      + l15][lq*8]);
    const bf16x8 a1 = ld_frag(&As[wr*32 + 16 + l15][lq*8]);
    const bf16x8 b0 = ld_frag(&Bs[wc*32      + l15][lq*8]);
    const bf16x8 b1 = ld_frag(&Bs[wc*32 + 16 + l15][lq*8]);
    acc[0][0] = mf(a0,b0,acc[0][0]);
    acc[0][1] = mf(a0,b1,acc[0][1]);
    acc[1][0] = mf(a1,b0,acc[1][0]);
    acc[1][1] = mf(a1,b1,acc[1][1]);
  }
  #pragma unroll
  for(int mi=0;mi<2;mi++)
    #pragma unroll
    for(int nj=0;nj<2;nj++){
      const int col = n0 + wc*32 + nj*16 + l15;
      const float bv = bias[wc0 + wc*32 + nj*16 + l15];
      #pragma unroll
      for(int rr=0;rr<4;rr++){
        const int row = m0 + wr*32 + mi*16 + lq*4 + rr;
        out[row*NQKV + col] = acc[mi][nj][rr] + bv;
      }
    }
}

// ---------------- K2: RoPE + pack (Q bf16, new K/V f32) ----------------
__global__ __launch_bounds__(128) void k_rope(
    const float* __restrict__ raw, const float* __restrict__ cosb, const float* __restrict__ sinb,
    unsigned short* __restrict__ Qb, float* __restrict__ KnF, float* __restrict__ VnF)
{
  const int r = blockIdx.x, hh = blockIdx.y, d = threadIdx.x;
  const int b = r>>5, s = r&31;
  const float cv = cosb[(b*S_+s)*HD_ + d];
  const float sv = sinb[(b*S_+s)*HD_ + d];
  const int dp = (d<64)? d+64 : d-64;
  if(hh < 16){
    const float x  = raw[r*NQKV + hh*HD_ + d];
    const float xo = raw[r*NQKV + hh*HD_ + dp];
    const float y  = x*cv + ((d<64)? -xo : xo)*sv;
    const int kvh = hh>>3, g = hh&7;
    Qb[((long)(b*NKV_+kvh)*M_ + g*S_ + s)*HD_ + d] = f2b(y);
  } else if(hh < 18){
    const int kvh = hh-16;
    const float x  = raw[r*NQKV + 2048 + kvh*HD_ + d];
    const float xo = raw[r*NQKV + 2048 + kvh*HD_ + dp];
    KnF[((long)(b*NKV_+kvh)*S_ + s)*HD_ + d] = x*cv + ((d<64)? -xo : xo)*sv;
  } else {
    const int kvh = hh-18;
    VnF[((long)(b*NKV_+kvh)*S_ + s)*HD_ + d] = raw[r*NQKV + 2304 + kvh*HD_ + d];
  }
}

// ---------------- K3: split-KV attention, 32x32 MFMA, in-register softmax ----
// grid (sp=32, kv=2, b=8) = 512 blocks -> 2 blocks/CU; 512 threads = 8 waves.
// Each block: 256 kv = 4 subtiles of KT_=64, online softmax w/ defer-rescale.
__global__ __launch_bounds__(512, 4) void k_attn(
    const unsigned short* __restrict__ Qb,
    const float* __restrict__ KnF, const float* __restrict__ VnF,
    const float* __restrict__ kc, const float* __restrict__ vc,
    const float* __restrict__ mask, const int* __restrict__ rpp,
    unsigned short* __restrict__ num, float* __restrict__ mbuf, float* __restrict__ lbuf)
{
  __shared__ __align__(16) unsigned short lds[2][2][KT_*128]; // [buf][K|Vt] 64KB
  const int sp = blockIdx.x, kvh = blockIdx.y, b = blockIdx.z;
  const int bk = b*NKV_ + kvh;
  const int rp = *rpp;
  const int t = threadIdx.x, lane = t&63, wid = t>>6;
  const int l31 = lane&31, hi = lane>>5;
  const int kvbase = sp*(KV_/NSP);
  // staging mappings
  const int krow = t>>3, kc0 = (t&7)*16;  // K: 64 rows x 8 col-eighths (16 f32 each)
  const int vhd  = t&127, vkq = t>>7;     // V: 128 hd cols x 4 kv-quarters (16 rows each)

  // Q fragments, held in registers for whole block
  bf16x8 qf[8];
  { const unsigned short* qp = Qb + ((long)bk*M_ + wid*32 + l31)*HD_;
    #pragma unroll
    for(int ks=0;ks<8;ks++) qf[ks] = ld_frag(qp + ks*16 + hi*8); }

  float4 vK4[4];
  float  vV[16];

  auto loadK = [&](int tt){
    const int kvr = kvbase + tt*KT_ + krow;
    const float* kp = (kvr>=rp && kvr<rp+S_)
        ? (KnF + ((long)bk*S_ + (kvr-rp))*HD_ + kc0)
        : (kc  + ((long)bk*KV_ + kvr)*HD_ + kc0);
    #pragma unroll
    for(int i=0;i<4;i++) vK4[i] = *(const float4*)(kp + i*4);
  };
  auto loadV = [&](int tt){
    #pragma unroll
    for(int m=0;m<16;m++){
      const int kvr = kvbase + tt*KT_ + vkq*16 + m;   // wave-uniform row
      const float* vp = (kvr>=rp && kvr<rp+S_)
          ? (VnF + ((long)bk*S_ + (kvr-rp))*HD_)
          : (vc  + ((long)bk*KV_ + kvr)*HD_);
      vV[m] = vp[vhd];
    }
  };
  auto writeK = [&](int bb){
    unsigned short* Sb = &lds[bb][0][0];
    uint4 w4;
    w4.x = pk2(vK4[0].x, vK4[0].y);  w4.y = pk2(vK4[0].z, vK4[0].w);
    w4.z = pk2(vK4[1].x, vK4[1].y);  w4.w = pk2(vK4[1].z, vK4[1].w);
    *(uint4*)(Sb + swiK(krow, kc0)) = w4;
    w4.x = pk2(vK4[2].x, vK4[2].y);  w4.y = pk2(vK4[2].z, vK4[2].w);
    w4.z = pk2(vK4[3].x, vK4[3].y);  w4.w = pk2(vK4[3].z, vK4[3].w);
    *(uint4*)(Sb + swiK(krow, kc0 + 8)) = w4;
  };
  auto writeV = [&](int bb){
    unsigned short* Sb = &lds[bb][1][0];
    uint4 w4;
    w4.x = pk2(vV[0], vV[1]);   w4.y = pk2(vV[2], vV[3]);
    w4.z = pk2(vV[4], vV[5]);   w4.w = pk2(vV[6], vV[7]);
    *(uint4*)(Sb + swiV(vhd, vkq*16)) = w4;
    w4.x = pk2(vV[8], vV[9]);   w4.y = pk2(vV[10], vV[11]);
    w4.z = pk2(vV[12], vV[13]); w4.w = pk2(vV[14], vV[15]);
    *(uint4*)(Sb + swiV(vhd, vkq*16 + 8)) = w4;
  };

  // prologue: stage subtile 0 into buf 0
  loadK(0); loadV(0);
  writeK(0); writeV(0);
  __syncthreads();

  f32x16 oc[4] = {};
  float m_run = -3.0e38f, l_run = 0.f;

  for(int tt=0; tt<NT_; tt++){
    const int cur = tt&1;
    if(tt<NT_-1) loadK(tt+1);                  // K loads in flight across compute
    // ---- QK^T: sc[kvt], kv = kvt*32 + (e&3)+8*(e>>2)+4*hi, q = l31 ----
    f32x16 sc[2] = {};
    { const unsigned short* Sk = &lds[cur][0][0];
      __builtin_amdgcn_s_setprio(1);
      #pragma unroll
      for(int ks=0;ks<8;ks++){
        #pragma unroll
        for(int kvt=0;kvt<2;kvt++)
          sc[kvt] = mf32(ld_frag(Sk + swiK(kvt*32 + l31, ks*16 + hi*8)), qf[ks], sc[kvt]);
      }
      __builtin_amdgcn_s_setprio(0);
    }
    if(tt<NT_-1) loadV(tt+1);                  // V loads in flight across softmax+PV
    // ---- mask + scale + tile max ----
    const float* mrow = mask + ((long)b*S_ + l31)*KV_ + kvbase + tt*KT_;
    float tmx = -3.0e38f;
    #pragma unroll
    for(int kvt=0;kvt<2;kvt++){
      #pragma unroll
      for(int r4=0;r4<4;r4++){
        const float4 mk = *(const float4*)(mrow + kvt*32 + r4*8 + hi*4);
        sc[kvt][r4*4+0] = sc[kvt][r4*4+0]*SCALE_ + mk.x;
        sc[kvt][r4*4+1] = sc[kvt][r4*4+1]*SCALE_ + mk.y;
        sc[kvt][r4*4+2] = sc[kvt][r4*4+2]*SCALE_ + mk.z;
        sc[kvt][r4*4+3] = sc[kvt][r4*4+3]*SCALE_ + mk.w;
        tmx = fmaxf(tmx, fmaxf(fmaxf(sc[kvt][r4*4+0], sc[kvt][r4*4+1]),
                               fmaxf(sc[kvt][r4*4+2], sc[kvt][r4*4+3])));
      }
    }
    tmx = fmaxf(tmx, __shfl_xor(tmx, 32, 64));
    // ---- T13 defer-rescale: only rescale when tile max grew past threshold ----
    if(!__all(tmx - m_run <= 8.0f)){
      const float mx  = fmaxf(m_run, tmx);
      const float scl = __expf(m_run - mx);    // first iter: exp(-huge)=0
      #pragma unroll
      for(int r4=0;r4<4;r4++)
        #pragma unroll
        for(int rr=0;rr<4;rr++){
          const float sq = __shfl(scl, rr + 8*r4 + 4*hi, 64);
          #pragma unroll
          for(int ht=0;ht<4;ht++) oc[ht][r4*4+rr] *= sq;
        }
      l_run *= scl;
      m_run = mx;
    }
    // ---- exp + per-lane partial sum (against possibly-stale m_run, bounded e^8) ----
    float psum = 0.f;
    #pragma unroll
    for(int kvt=0;kvt<2;kvt++)
      #pragma unroll
      for(int e=0;e<16;e++){
        const float p = __expf(sc[kvt][e] - m_run);
        sc[kvt][e] = p; psum += p;
      }
    l_run += psum;
    // ---- pack P to bf16 pairs ----
    unsigned w_[2][4][2];
    #pragma unroll
    for(int kvt=0;kvt<2;kvt++)
      #pragma unroll
      for(int r4=0;r4<4;r4++){
        w_[kvt][r4][0] = pk2(sc[kvt][r4*4+0], sc[kvt][r4*4+1]);
        w_[kvt][r4][1] = pk2(sc[kvt][r4*4+2], sc[kvt][r4*4+3]);
      }
    // ---- PV: O[q][hd] += P x V ----
    { const unsigned short* Sv = &lds[cur][1][0];
      __builtin_amdgcn_s_setprio(1);
      #pragma unroll
      for(int kvs=0;kvs<4;kvs++){
        const int kvt = kvs>>1, k2 = (kvs&1)*2;
        const unsigned wa0 = w_[kvt][k2  ][0], wa1 = w_[kvt][k2  ][1];
        const unsigned wb0 = w_[kvt][k2+1][0], wb1 = w_[kvt][k2+1][1];
        const unsigned own0 = hi? wb0:wa0, own1 = hi? wb1:wa1;
        const unsigned snd0 = hi? wa0:wb0, snd1 = hi? wa1:wb1;
        const unsigned rcv0 = __shfl_xor(snd0, 32, 64);
        const unsigned rcv1 = __shfl_xor(snd1, 32, 64);
        union{ unsigned u[4]; bf16x8 v; } ap;
        ap.u[0] = hi? rcv0:own0;  ap.u[1] = hi? rcv1:own1;
        ap.u[2] = hi? own0:rcv0;  ap.u[3] = hi? own1:rcv1;
        #pragma unroll
        for(int ht=0;ht<4;ht++)
          oc[ht] = mf32(ap.v, ld_frag(Sv + swiV(ht*32 + l31, kvs*16 + hi*8)), oc[ht]);
      }
      __builtin_amdgcn_s_setprio(0);
    }
    // ---- stage next subtile into other buffer ----
    if(tt<NT_-1){ writeK(cur^1); writeV(cur^1); }
    __syncthreads();
  }

  // ---- epilogue: write partials ----
  const float l_tot = l_run + __shfl_xor(l_run, 32, 64);
  if(lane < 32){
    const long base = ((long)bk*NSP + sp)*M_ + wid*32 + lane;
    mbuf[base] = m_run;
    lbuf[base] = l_tot;
  }
  unsigned short* np_ = num + (((long)bk*NSP + sp)*M_ + wid*32)*HD_;
  #pragma unroll
  for(int ht=0;ht<4;ht++)
    #pragma unroll
    for(int r4=0;r4<4;r4++)
      #pragma unroll
      for(int rr=0;rr<4;rr++){
        const int q = rr + 8*r4 + 4*hi;
        np_[(long)q*HD_ + ht*32 + l31] = f2b(oc[ht][r4*4+rr]);
      }
}

// ---------------- K4: combine split-KV partials ----------------
__global__ __launch_bounds__(128) void k_comb(
    const unsigned short* __restrict__ num, const float* __restrict__ mbuf,
    const float* __restrict__ lbuf, unsigned short* __restrict__ attnb)
{
  const int q = blockIdx.x, kvh = blockIdx.y, b = blockIdx.z, d = threadIdx.x;
  const int bk = b*NKV_ + kvh;
  float M = -3.0e38f;
  #pragma unroll
  for(int c=0;c<NSP;c++) M = fmaxf(M, mbuf[((long)bk*NSP + c)*M_ + q]);
  float den = 0.f, acc = 0.f;
  #pragma unroll
  for(int c=0;c<NSP;c++){
    const long ix = ((long)bk*NSP + c)*M_ + q;
    const float w = __expf(mbuf[ix] - M);
    den += lbuf[ix]*w;
    acc += w * b2f(num[ix*HD_ + d]);
  }
  const int g = q>>5, s = q&31, h = kvh*G_ + g;
  attnb[((long)(b*S_+s))*2048 + h*HD_ + d] = f2b(acc/den);
}

// ---------------- K5: output projection GEMM ----------------
__global__ __launch_bounds__(256) void k_gemm_o(
    const unsigned short* __restrict__ A,
    const float* __restrict__ W,
    float* __restrict__ out)
{
  __shared__ unsigned short As[64][56];
  __shared__ unsigned short Bs[64][56];
  const int n0 = blockIdx.x*64, m0 = blockIdx.y*64;
  const int t = threadIdx.x, lane = t&63, wid = t>>6;
  const int wr = wid>>1, wc = wid&1, l15 = lane&15, lq = lane>>4;
  const int ar = t>>2,  ac = (t&3)*8;
  const int bk = t>>5,  bn = (t&31)*2;
  f32x4 acc[2][2] = {};
  for(int k0 = 0; k0 < 2048; k0 += 32){
    __syncthreads();
    *(uint4*)(&As[ar][ac]) = *(const uint4*)(A + (m0+ar)*2048 + k0 + ac);
    #pragma unroll
    for(int p=0;p<4;p++){
      const int kk = bk + p*8;
      const float2 wv = *(const float2*)(W + (long)(k0+kk)*2048 + n0 + bn);
      Bs[bn  ][kk] = f2b(wv.x);
      Bs[bn+1][kk] = f2b(wv.y);
    }
    __syncthreads();
    const bf16x8 a0 = ld_frag(&As[wr*32      + l15][lq*8]);
    const bf16x8 a1 = ld_frag(&As[wr*32 + 16 + l15][lq*8]);
    const bf16x8 b0 = ld_frag(&Bs[wc*32      + l15][lq*8]);
    const bf16x8 b1 = ld_frag(&Bs[wc*32 + 16 + l15][lq*8]);
    acc[0][0] = mf(a0,b0,acc[0][0]);
    acc[0][1] = mf(a0,b1,acc[0][1]);
    acc[1][0] = mf(a1,b0,acc[1][0]);
    acc[1][1] = mf(a1,b1,acc[1][1]);
  }
  #pragma unroll
  for(int mi=0;mi<2;mi++)
    #pragma unroll
    for(int nj=0;nj<2;nj++){
      const int col = n0 + wc*32 + nj*16 + l15;
      #pragma unroll
      for(int rr=0;rr<4;rr++){
        const int row = m0 + wr*32 + mi*16 + lq*4 + rr;
        out[row*2048 + col] = acc[mi][nj][rr];
      }
    }
}

extern "C" void kernel_launch(void* const* d_in, const int* in_sizes, int n_in,
                              void* d_out, int out_size, void* d_ws, size_t ws_size,
                              hipStream_t stream){
  (void)in_sizes; (void)n_in; (void)out_size; (void)ws_size;
  const float* hs   = (const float*)d_in[0];
  const float* cosb = (const float*)d_in[1];
  const float* sinb = (const float*)d_in[2];
  const float* kc   = (const float*)d_in[3];
  const float* vc   = (const float*)d_in[4];
  const float* mask = (const float*)d_in[5];
  const int*   rp   = (const int*)  d_in[6];
  const float* qw   = (const float*)d_in[7];
  const float* qb   = (const float*)d_in[8];
  const float* kw   = (const float*)d_in[9];
  const float* kb   = (const float*)d_in[10];
  const float* vw   = (const float*)d_in[11];
  const float* vb   = (const float*)d_in[12];
  const float* ow   = (const float*)d_in[13];
  char* ws = (char*)d_ws;
  // ws layout (bytes)
  unsigned short* hsb   = (unsigned short*)(ws + 0);          // 1,048,576
  float*          raw   = (float*)         (ws + 1048576);    // 2,621,440
  unsigned short* Qb    = (unsigned short*)(ws + 3670016);    // 1,048,576
  float*          KnF   = (float*)         (ws + 4718592);    //   262,144
  float*          VnF   = (float*)         (ws + 4980736);    //   262,144
  unsigned short* attnb = (unsigned short*)(ws + 5242880);    // 1,048,576
  float*          mbuf  = (float*)         (ws + 6291456);    //   524,288
  float*          lbuf  = (float*)         (ws + 6815744);    //   524,288
  unsigned short* num   = (unsigned short*)(ws + 7340032);    // 33,554,432
  float* outp = (float*)d_out;

  k_cvt     <<<dim3(512),      dim3(256), 0, stream>>>(hs, hsb);
  k_gemm_qkv<<<dim3(40,4),     dim3(256), 0, stream>>>(hsb, qw,kw,vw, qb,kb,vb, raw);
  k_rope    <<<dim3(256,20),   dim3(128), 0, stream>>>(raw, cosb, sinb, Qb, KnF, VnF);
  k_attn    <<<dim3(NSP,2,8),  dim3(512), 0, stream>>>(Qb, KnF, VnF, kc, vc, mask, rp, num, mbuf, lbuf);
  k_comb    <<<dim3(256,2,8),  dim3(128), 0, stream>>>(num, mbuf, lbuf, attnb);
  k_gemm_o  <<<dim3(32,4),     dim3(256), 0, stream>>>(attnb, ow, outp);
}

// Round 5
// 249.770 us; speedup vs baseline: 1.4189x; 1.4189x over previous
//
#include <hip/hip_runtime.h>
#include <hip/hip_bf16.h>

#define B_    8
#define S_    32
#define H_    2048
#define NH_   16
#define NKV_  2
#define HD_   128
#define KV_   8192
#define G_    8
#define M_    256      /* B*S */
#define NQKV  2560     /* fused proj N: 2048 q | 256 k | 256 v */
#define NSP   16       /* kv splits */
#define KT_   128      /* kv subtile (one tile image) */
#define NT_   4        /* subtiles per block */
#define NTILE 64       /* KV_/KT_ tiles per bk */
#define SCALE_ 0.08838834764831845f

typedef __bf16 bf16x8 __attribute__((ext_vector_type(8)));
typedef float  f32x4  __attribute__((ext_vector_type(4)));
typedef float  f32x16 __attribute__((ext_vector_type(16)));

__device__ __forceinline__ unsigned short f2b(float f){
  unsigned u = __float_as_uint(f);
  u = u + 0x7FFFu + ((u>>16)&1u);           // RNE f32->bf16
  return (unsigned short)(u>>16);
}
__device__ __forceinline__ float b2f(unsigned short h){
  return __uint_as_float(((unsigned)h)<<16);
}
__device__ __forceinline__ unsigned pk2(float a, float b){
  return (unsigned)f2b(a) | ((unsigned)f2b(b)<<16);
}
__device__ __forceinline__ bf16x8 ld_frag(const unsigned short* p){
  union { uint4 u; bf16x8 b; } cv;
  cv.u = *(const uint4*)p;
  return cv.b;
}
__device__ __forceinline__ f32x4 mf(bf16x8 a, bf16x8 b, f32x4 c){
  return __builtin_amdgcn_mfma_f32_16x16x32_bf16(a, b, c, 0, 0, 0);
}
__device__ __forceinline__ f32x16 mf32(bf16x8 a, bf16x8 b, f32x16 c){
  return __builtin_amdgcn_mfma_f32_32x32x16_bf16(a, b, c, 0, 0, 0);
}
// K tile swizzle: 128 rows x 128 cols (shorts), 16B-group XOR (16-way spread)
__device__ __forceinline__ int swiK(int row, int col){
  return row*128 + (col ^ ((((row)&15) ^ ((row>>1)&8)) << 3));
}
// Vt tile swizzle: 128 hd-rows x 128 kv-cols (shorts), 16-way spread
__device__ __forceinline__ int swiV(int row, int col){
  return row*128 + (col ^ (((row)&15) << 3));
}
// async global->LDS, 16B per lane; LDS dest = wave-uniform base + lane*16
__device__ __forceinline__ void gll16(const unsigned short* g, unsigned short* l){
  __builtin_amdgcn_global_load_lds(
      (const __attribute__((address_space(1))) unsigned int*)g,
      (__attribute__((address_space(3))) unsigned int*)l,
      16, 0, 0);
}

// ---------------- K0: hidden_states f32 -> bf16 ----------------
__global__ __launch_bounds__(256) void k_cvt(const float* __restrict__ x,
                                             unsigned short* __restrict__ y){
  const int i = (blockIdx.x*256 + threadIdx.x)*4;
  const float4 v = *(const float4*)(x + i);
  ushort4 o; o.x=f2b(v.x); o.y=f2b(v.y); o.z=f2b(v.z); o.w=f2b(v.w);
  *(ushort4*)(y + i) = o;
}

// ---------------- K1: fused QKV projection GEMM (bf16 MFMA) ----------------
__global__ __launch_bounds__(256) void k_gemm_qkv(
    const unsigned short* __restrict__ A,
    const float* __restrict__ qw, const float* __restrict__ kw, const float* __restrict__ vw,
    const float* __restrict__ qbv, const float* __restrict__ kbv, const float* __restrict__ vbv,
    float* __restrict__ out)
{
  __shared__ unsigned short As[64][56];
  __shared__ unsigned short Bs[64][56];
  const int n0 = blockIdx.x*64, m0 = blockIdx.y*64;
  const float* W; const float* bias; int ldw, wc0;
  if(n0 < 2048)      { W=qw; bias=qbv; ldw=2048; wc0=n0; }
  else if(n0 < 2304) { W=kw; bias=kbv; ldw=256;  wc0=n0-2048; }
  else               { W=vw; bias=vbv; ldw=256;  wc0=n0-2304; }
  const int t = threadIdx.x, lane = t&63, wid = t>>6;
  const int wr = wid>>1, wc = wid&1, l15 = lane&15, lq = lane>>4;
  const int ar = t>>2,  ac = (t&3)*8;
  const int bk = t>>5,  bn = (t&31)*2;
  f32x4 acc[2][2] = {};
  for(int k0 = 0; k0 < 2048; k0 += 32){
    __syncthreads();
    *(uint4*)(&As[ar][ac]) = *(const uint4*)(A + (m0+ar)*2048 + k0 + ac);
    #pragma unroll
    for(int p=0;p<4;p++){
      const int kk = bk + p*8;
      const float2 wv = *(const float2*)(W + (long)(k0+kk)*ldw + wc0 + bn);
      Bs[bn  ][kk] = f2b(wv.x);
      Bs[bn+1][kk] = f2b(wv.y);
    }
    __syncthreads();
    const bf16x8 a0 = ld_frag(&As[wr*32      + l15][lq*8]);
    const bf16x8 a1 = ld_frag(&As[wr*32 + 16 + l15][lq*8]);
    const bf16x8 b0 = ld_frag(&Bs[wc*32      + l15][lq*8]);
    const bf16x8 b1 = ld_frag(&Bs[wc*32 + 16 + l15][lq*8]);
    acc[0][0] = mf(a0,b0,acc[0][0]);
    acc[0][1] = mf(a0,b1,acc[0][1]);
    acc[1][0] = mf(a1,b0,acc[1][0]);
    acc[1][1] = mf(a1,b1,acc[1][1]);
  }
  #pragma unroll
  for(int mi=0;mi<2;mi++)
    #pragma unroll
    for(int nj=0;nj<2;nj++){
      const int col = n0 + wc*32 + nj*16 + l15;
      const float bv = bias[wc0 + wc*32 + nj*16 + l15];
      #pragma unroll
      for(int rr=0;rr<4;rr++){
        const int row = m0 + wr*32 + mi*16 + lq*4 + rr;
        out[row*NQKV + col] = acc[mi][nj][rr] + bv;
      }
    }
}

// ---------------- K2: RoPE + pack (Q bf16, new K/V f32) ----------------
__global__ __launch_bounds__(128) void k_rope(
    const float* __restrict__ raw, const float* __restrict__ cosb, const float* __restrict__ sinb,
    unsigned short* __restrict__ Qb, float* __restrict__ KnF, float* __restrict__ VnF)
{
  const int r = blockIdx.x, hh = blockIdx.y, d = threadIdx.x;
  const int b = r>>5, s = r&31;
  const float cv = cosb[(b*S_+s)*HD_ + d];
  const float sv = sinb[(b*S_+s)*HD_ + d];
  const int dp = (d<64)? d+64 : d-64;
  if(hh < 16){
    const float x  = raw[r*NQKV + hh*HD_ + d];
    const float xo = raw[r*NQKV + hh*HD_ + dp];
    const float y  = x*cv + ((d<64)? -xo : xo)*sv;
    const int kvh = hh>>3, g = hh&7;
    Qb[((long)(b*NKV_+kvh)*M_ + g*S_ + s)*HD_ + d] = f2b(y);
  } else if(hh < 18){
    const int kvh = hh-16;
    const float x  = raw[r*NQKV + 2048 + kvh*HD_ + d];
    const float xo = raw[r*NQKV + 2048 + kvh*HD_ + dp];
    KnF[((long)(b*NKV_+kvh)*S_ + s)*HD_ + d] = x*cv + ((d<64)? -xo : xo)*sv;
  } else {
    const int kvh = hh-18;
    VnF[((long)(b*NKV_+kvh)*S_ + s)*HD_ + d] = raw[r*NQKV + 2304 + kvh*HD_ + d];
  }
}

// ---------------- K2b: K/V cache -> pre-swizzled bf16 tile images ----------
// grid (tile=64, bk=16), 512 thr. Folds replace-window + V transpose + swizzle.
__global__ __launch_bounds__(512) void k_kvcvt(
    const float* __restrict__ kc, const float* __restrict__ vc,
    const float* __restrict__ KnF, const float* __restrict__ VnF,
    const int* __restrict__ rpp,
    unsigned short* __restrict__ ktg, unsigned short* __restrict__ vtg)
{
  const int tile = blockIdx.x, bk = blockIdx.y;
  const int rp = *rpp;
  const int t = threadIdx.x;
  const long tbase = ((long)bk*NTILE + tile)*(KT_*HD_);
  // ---- K image: row-major [kv 128][hd 128], swizzled ----
  {
    const int row = t>>2, c0 = (t&3)*32;
    const int kvr = tile*KT_ + row;
    const float* src = (kvr>=rp && kvr<rp+S_)
        ? (KnF + ((long)bk*S_ + (kvr-rp))*HD_ + c0)
        : (kc  + ((long)bk*KV_ + kvr)*HD_ + c0);
    #pragma unroll
    for(int i=0;i<4;i++){
      const float4 a = *(const float4*)(src + i*8);
      const float4 c = *(const float4*)(src + i*8 + 4);
      uint4 w; w.x=pk2(a.x,a.y); w.y=pk2(a.z,a.w); w.z=pk2(c.x,c.y); w.w=pk2(c.z,c.w);
      *(uint4*)(ktg + tbase + swiK(row, c0 + i*8)) = w;
    }
  }
  // ---- V^T image: [hd 128][kv 128], swizzled ----
  {
    const int hd = t&127, g0 = (t>>7)*4;
    #pragma unroll
    for(int g2=0; g2<4; g2++){
      const int kvg = g0 + g2;
      float v[8];
      #pragma unroll
      for(int j=0;j<8;j++){
        const int kvr = tile*KT_ + kvg*8 + j;
        v[j] = (kvr>=rp && kvr<rp+S_)
            ? VnF[((long)bk*S_ + (kvr-rp))*HD_ + hd]
            : vc [((long)bk*KV_ + kvr)*HD_ + hd];
      }
      uint4 w; w.x=pk2(v[0],v[1]); w.y=pk2(v[2],v[3]);
               w.z=pk2(v[4],v[5]); w.w=pk2(v[6],v[7]);
      *(uint4*)(vtg + tbase + swiV(hd, kvg*8)) = w;
    }
  }
}

// ---------------- K3: split-KV attention, gll-staged bf16 tiles -------------
// grid (sp=16, kv=2, b=8) = 256 blocks; 512 thr = 8 waves; wave owns 32 q rows.
// Each block: 512 kv = 4 tiles of 128, online softmax w/ defer-rescale.
__global__ __launch_bounds__(512, 2) void k_attn(
    const unsigned short* __restrict__ Qb,
    const unsigned short* __restrict__ ktg, const unsigned short* __restrict__ vtg,
    const float* __restrict__ mask,
    unsigned short* __restrict__ num, float* __restrict__ mbuf, float* __restrict__ lbuf)
{
  __shared__ __align__(16) unsigned short lds[2][2][KT_*HD_]; // 128 KB
  const int sp = blockIdx.x, kvh = blockIdx.y, b = blockIdx.z;
  const int bk = b*NKV_ + kvh;
  const int t = threadIdx.x, lane = t&63, wid = t>>6;
  const int l31 = lane&31, hi = lane>>5;

  // Q fragments, held in registers for whole block
  bf16x8 qf[8];
  { const unsigned short* qp = Qb + ((long)bk*M_ + wid*32 + l31)*HD_;
    #pragma unroll
    for(int ks=0;ks<8;ks++) qf[ks] = ld_frag(qp + ks*16 + hi*8); }

  auto stage = [&](int tt, int bb){
    const long tb = ((long)bk*NTILE + sp*NT_ + tt)*(KT_*HD_);
    const unsigned short* ks = ktg + tb;
    const unsigned short* vs = vtg + tb;
    unsigned short* lk = &lds[bb][0][0];
    unsigned short* lv = &lds[bb][1][0];
    #pragma unroll
    for(int r=0;r<4;r++){
      const int cb = (wid*4+r)*512;          // chunk base (shorts), wave-uniform
      gll16(ks + cb + lane*8, lk + cb);
      gll16(vs + cb + lane*8, lv + cb);
    }
  };

  stage(0, 0);
  __syncthreads();

  f32x16 oc[4] = {};
  float m_run = -3.0e38f, l_run = 0.f;

  for(int tt=0; tt<NT_; tt++){
    const int cur = tt&1;
    if(tt<NT_-1) stage(tt+1, cur^1);          // async, drains at the barrier
    // ---- QK^T: sc[kvt], kv-row = kvt*32 + (e&3)+8*(e>>2)+4*hi, q = l31 ----
    f32x16 sc[4] = {};
    { const unsigned short* Sk = &lds[cur][0][0];
      __builtin_amdgcn_s_setprio(1);
      #pragma unroll
      for(int ks=0;ks<8;ks++){
        #pragma unroll
        for(int kvt=0;kvt<4;kvt++)
          sc[kvt] = mf32(ld_frag(Sk + swiK(kvt*32 + l31, ks*16 + hi*8)), qf[ks], sc[kvt]);
      }
      __builtin_amdgcn_s_setprio(0);
    }
    // ---- mask + scale + tile max ----
    const float* mrow = mask + ((long)b*S_ + l31)*KV_ + sp*(KV_/NSP) + tt*KT_;
    float tmx = -3.0e38f;
    #pragma unroll
    for(int kvt=0;kvt<4;kvt++){
      #pragma unroll
      for(int r4=0;r4<4;r4++){
        const float4 mk = *(const float4*)(mrow + kvt*32 + r4*8 + hi*4);
        sc[kvt][r4*4+0] = sc[kvt][r4*4+0]*SCALE_ + mk.x;
        sc[kvt][r4*4+1] = sc[kvt][r4*4+1]*SCALE_ + mk.y;
        sc[kvt][r4*4+2] = sc[kvt][r4*4+2]*SCALE_ + mk.z;
        sc[kvt][r4*4+3] = sc[kvt][r4*4+3]*SCALE_ + mk.w;
        tmx = fmaxf(tmx, fmaxf(fmaxf(sc[kvt][r4*4+0], sc[kvt][r4*4+1]),
                               fmaxf(sc[kvt][r4*4+2], sc[kvt][r4*4+3])));
      }
    }
    tmx = fmaxf(tmx, __shfl_xor(tmx, 32, 64));
    // ---- T13 defer-rescale ----
    if(!__all(tmx - m_run <= 8.0f)){
      const float mx  = fmaxf(m_run, tmx);
      const float scl = __expf(m_run - mx);   // first iter: exp(-huge)=0
      #pragma unroll
      for(int r4=0;r4<4;r4++)
        #pragma unroll
        for(int rr=0;rr<4;rr++){
          const float sq = __shfl(scl, rr + 8*r4 + 4*hi, 64);
          #pragma unroll
          for(int ht=0;ht<4;ht++) oc[ht][r4*4+rr] *= sq;
        }
      l_run *= scl;
      m_run = mx;
    }
    // ---- exp + per-lane partial sum ----
    float psum = 0.f;
    #pragma unroll
    for(int kvt=0;kvt<4;kvt++)
      #pragma unroll
      for(int e=0;e<16;e++){
        const float p = __expf(sc[kvt][e] - m_run);
        sc[kvt][e] = p; psum += p;
      }
    l_run += psum;
    // ---- pack P to bf16 pairs ----
    unsigned w_[4][4][2];
    #pragma unroll
    for(int kvt=0;kvt<4;kvt++)
      #pragma unroll
      for(int r4=0;r4<4;r4++){
        w_[kvt][r4][0] = pk2(sc[kvt][r4*4+0], sc[kvt][r4*4+1]);
        w_[kvt][r4][1] = pk2(sc[kvt][r4*4+2], sc[kvt][r4*4+3]);
      }
    // ---- PV: O[q][hd] += P x V ----
    { const unsigned short* Sv = &lds[cur][1][0];
      __builtin_amdgcn_s_setprio(1);
      #pragma unroll
      for(int kvs=0;kvs<8;kvs++){
        const int kvt = kvs>>1, k2 = (kvs&1)*2;
        const unsigned wa0 = w_[kvt][k2  ][0], wa1 = w_[kvt][k2  ][1];
        const unsigned wb0 = w_[kvt][k2+1][0], wb1 = w_[kvt][k2+1][1];
        const unsigned own0 = hi? wb0:wa0, own1 = hi? wb1:wa1;
        const unsigned snd0 = hi? wa0:wb0, snd1 = hi? wa1:wb1;
        const unsigned rcv0 = __shfl_xor(snd0, 32, 64);
        const unsigned rcv1 = __shfl_xor(snd1, 32, 64);
        union{ unsigned u[4]; bf16x8 v; } ap;
        ap.u[0] = hi? rcv0:own0;  ap.u[1] = hi? rcv1:own1;
        ap.u[2] = hi? own0:rcv0;  ap.u[3] = hi? own1:rcv1;
        #pragma unroll
        for(int ht=0;ht<4;ht++)
          oc[ht] = mf32(ap.v, ld_frag(Sv + swiV(ht*32 + l31, kvs*16 + hi*8)), oc[ht]);
      }
      __builtin_amdgcn_s_setprio(0);
    }
    __syncthreads();   // drains prefetch vmcnt + lds reads; swap buffers
  }

  // ---- epilogue: write partials ----
  const float l_tot = l_run + __shfl_xor(l_run, 32, 64);
  if(lane < 32){
    const long base = ((long)bk*NSP + sp)*M_ + wid*32 + lane;
    mbuf[base] = m_run;
    lbuf[base] = l_tot;
  }
  unsigned short* np_ = num + (((long)bk*NSP + sp)*M_ + wid*32)*HD_;
  #pragma unroll
  for(int ht=0;ht<4;ht++)
    #pragma unroll
    for(int r4=0;r4<4;r4++)
      #pragma unroll
      for(int rr=0;rr<4;rr++){
        const int q = rr + 8*r4 + 4*hi;
        np_[(long)q*HD_ + ht*32 + l31] = f2b(oc[ht][r4*4+rr]);
      }
}

// ---------------- K4: combine split-KV partials ----------------
__global__ __launch_bounds__(128) void k_comb(
    const unsigned short* __restrict__ num, const float* __restrict__ mbuf,
    const float* __restrict__ lbuf, unsigned short* __restrict__ attnb)
{
  const int q = blockIdx.x, kvh = blockIdx.y, b = blockIdx.z, d = threadIdx.x;
  const int bk = b*NKV_ + kvh;
  float M = -3.0e38f;
  #pragma unroll
  for(int c=0;c<NSP;c++) M = fmaxf(M, mbuf[((long)bk*NSP + c)*M_ + q]);
  float den = 0.f, acc = 0.f;
  #pragma unroll
  for(int c=0;c<NSP;c++){
    const long ix = ((long)bk*NSP + c)*M_ + q;
    const float w = __expf(mbuf[ix] - M);
    den += lbuf[ix]*w;
    acc += w * b2f(num[ix*HD_ + d]);
  }
  const int g = q>>5, s = q&31, h = kvh*G_ + g;
  attnb[((long)(b*S_+s))*2048 + h*HD_ + d] = f2b(acc/den);
}

// ---------------- K5: output projection GEMM ----------------
__global__ __launch_bounds__(256) void k_gemm_o(
    const unsigned short* __restrict__ A,
    const float* __restrict__ W,
    float* __restrict__ out)
{
  __shared__ unsigned short As[64][56];
  __shared__ unsigned short Bs[64][56];
  const int n0 = blockIdx.x*64, m0 = blockIdx.y*64;
  const int t = threadIdx.x, lane = t&63, wid = t>>6;
  const int wr = wid>>1, wc = wid&1, l15 = lane&15, lq = lane>>4;
  const int ar = t>>2,  ac = (t&3)*8;
  const int bk = t>>5,  bn = (t&31)*2;
  f32x4 acc[2][2] = {};
  for(int k0 = 0; k0 < 2048; k0 += 32){
    __syncthreads();
    *(uint4*)(&As[ar][ac]) = *(const uint4*)(A + (m0+ar)*2048 + k0 + ac);
    #pragma unroll
    for(int p=0;p<4;p++){
      const int kk = bk + p*8;
      const float2 wv = *(const float2*)(W + (long)(k0+kk)*2048 + n0 + bn);
      Bs[bn  ][kk] = f2b(wv.x);
      Bs[bn+1][kk] = f2b(wv.y);
    }
    __syncthreads();
    const bf16x8 a0 = ld_frag(&As[wr*32      + l15][lq*8]);
    const bf16x8 a1 = ld_frag(&As[wr*32 + 16 + l15][lq*8]);
    const bf16x8 b0 = ld_frag(&Bs[wc*32      + l15][lq*8]);
    const bf16x8 b1 = ld_frag(&Bs[wc*32 + 16 + l15][lq*8]);
    acc[0][0] = mf(a0,b0,acc[0][0]);
    acc[0][1] = mf(a0,b1,acc[0][1]);
    acc[1][0] = mf(a1,b0,acc[1][0]);
    acc[1][1] = mf(a1,b1,acc[1][1]);
  }
  #pragma unroll
  for(int mi=0;mi<2;mi++)
    #pragma unroll
    for(int nj=0;nj<2;nj++){
      const int col = n0 + wc*32 + nj*16 + l15;
      #pragma unroll
      for(int rr=0;rr<4;rr++){
        const int row = m0 + wr*32 + mi*16 + lq*4 + rr;
        out[row*2048 + col] = acc[mi][nj][rr];
      }
    }
}

extern "C" void kernel_launch(void* const* d_in, const int* in_sizes, int n_in,
                              void* d_out, int out_size, void* d_ws, size_t ws_size,
                              hipStream_t stream){
  (void)in_sizes; (void)n_in; (void)out_size; (void)ws_size;
  const float* hs   = (const float*)d_in[0];
  const float* cosb = (const float*)d_in[1];
  const float* sinb = (const float*)d_in[2];
  const float* kc   = (const float*)d_in[3];
  const float* vc   = (const float*)d_in[4];
  const float* mask = (const float*)d_in[5];
  const int*   rp   = (const int*)  d_in[6];
  const float* qw   = (const float*)d_in[7];
  const float* qb   = (const float*)d_in[8];
  const float* kw   = (const float*)d_in[9];
  const float* kb   = (const float*)d_in[10];
  const float* vw   = (const float*)d_in[11];
  const float* vb   = (const float*)d_in[12];
  const float* ow   = (const float*)d_in[13];
  char* ws = (char*)d_ws;
  // ws layout (bytes); tiles last so a ws shortfall fails loudly
  unsigned short* hsb   = (unsigned short*)(ws + 0);          // 1,048,576
  float*          raw   = (float*)         (ws + 1048576);    // 2,621,440
  unsigned short* Qb    = (unsigned short*)(ws + 3670016);    // 1,048,576
  float*          KnF   = (float*)         (ws + 4718592);    //   262,144
  float*          VnF   = (float*)         (ws + 4980736);    //   262,144
  unsigned short* attnb = (unsigned short*)(ws + 5242880);    // 1,048,576
  float*          mbuf  = (float*)         (ws + 6291456);    //   262,144
  float*          lbuf  = (float*)         (ws + 6553600);    //   262,144
  unsigned short* num   = (unsigned short*)(ws + 6815744);    // 16,777,216
  unsigned short* ktg   = (unsigned short*)(ws + 23592960);   // 33,554,432
  unsigned short* vtg   = (unsigned short*)(ws + 57147392);   // 33,554,432  (end ~90.7 MB)
  float* outp = (float*)d_out;

  k_cvt     <<<dim3(512),       dim3(256), 0, stream>>>(hs, hsb);
  k_gemm_qkv<<<dim3(40,4),      dim3(256), 0, stream>>>(hsb, qw,kw,vw, qb,kb,vb, raw);
  k_rope    <<<dim3(256,20),    dim3(128), 0, stream>>>(raw, cosb, sinb, Qb, KnF, VnF);
  k_kvcvt   <<<dim3(NTILE,16),  dim3(512), 0, stream>>>(kc, vc, KnF, VnF, rp, ktg, vtg);
  k_attn    <<<dim3(NSP,2,8),   dim3(512), 0, stream>>>(Qb, ktg, vtg, mask, num, mbuf, lbuf);
  k_comb    <<<dim3(256,2,8),   dim3(128), 0, stream>>>(num, mbuf, lbuf, attnb);
  k_gemm_o  <<<dim3(32,4),      dim3(256), 0, stream>>>(attnb, ow, outp);
}

// Round 6
// 199.723 us; speedup vs baseline: 1.7745x; 1.2506x over previous
//
#include <hip/hip_runtime.h>
#include <hip/hip_bf16.h>

#define B_    8
#define S_    32
#define H_    2048
#define NH_   16
#define NKV_  2
#define HD_   128
#define KV_   8192
#define G_    8
#define M_    256      /* B*S */
#define NQKV  2560     /* fused proj N: 2048 q | 256 k | 256 v */
#define NSP   16       /* kv splits */
#define KT_   64       /* kv subtile */
#define NT_   8        /* subtiles per block = KV_/NSP/KT_ */
#define SCALE_ 0.08838834764831845f

typedef __bf16 bf16x8 __attribute__((ext_vector_type(8)));
typedef float  f32x4  __attribute__((ext_vector_type(4)));
typedef float  f32x16 __attribute__((ext_vector_type(16)));

__device__ __forceinline__ unsigned short f2b(float f){
  unsigned u = __float_as_uint(f);
  u = u + 0x7FFFu + ((u>>16)&1u);           // RNE f32->bf16
  return (unsigned short)(u>>16);
}
__device__ __forceinline__ float b2f(unsigned short h){
  return __uint_as_float(((unsigned)h)<<16);
}
__device__ __forceinline__ unsigned pk2(float a, float b){
  return (unsigned)f2b(a) | ((unsigned)f2b(b)<<16);
}
__device__ __forceinline__ bf16x8 ld_frag(const unsigned short* p){
  union { uint4 u; bf16x8 b; } cv;
  cv.u = *(const uint4*)p;
  return cv.b;
}
__device__ __forceinline__ f32x4 mf(bf16x8 a, bf16x8 b, f32x4 c){
  return __builtin_amdgcn_mfma_f32_16x16x32_bf16(a, b, c, 0, 0, 0);
}
__device__ __forceinline__ f32x16 mf32(bf16x8 a, bf16x8 b, f32x16 c){
  return __builtin_amdgcn_mfma_f32_32x32x16_bf16(a, b, c, 0, 0, 0);
}
// K tile swizzle: 64 rows x 128 cols (shorts), 16B-group XOR
__device__ __forceinline__ int swiK(int row, int col){
  return row*128 + (col ^ ((((row)&15) ^ ((row>>1)&8)) << 3));
}
// Vt tile swizzle: 128 rows x 64 cols (shorts)
__device__ __forceinline__ int swiV(int row, int col){
  return row*64 + (col ^ (((row)&7) << 3));
}

// ---------------- K0: hidden_states f32 -> bf16 ----------------
__global__ __launch_bounds__(256) void k_cvt(const float* __restrict__ x,
                                             unsigned short* __restrict__ y){
  const int i = (blockIdx.x*256 + threadIdx.x)*4;
  const float4 v = *(const float4*)(x + i);
  ushort4 o; o.x=f2b(v.x); o.y=f2b(v.y); o.z=f2b(v.z); o.w=f2b(v.w);
  *(ushort4*)(y + i) = o;
}

// ---------------- K1: fused QKV projection GEMM, split-K=2 ----------------
// out: rawp[2][M_][NQKV]; z-half kz covers K = kz*1024..+1024. Bias on kz=0.
__global__ __launch_bounds__(256) void k_gemm_qkv(
    const unsigned short* __restrict__ A,
    const float* __restrict__ qw, const float* __restrict__ kw, const float* __restrict__ vw,
    const float* __restrict__ qbv, const float* __restrict__ kbv, const float* __restrict__ vbv,
    float* __restrict__ rawp)
{
  __shared__ unsigned short As[64][56];
  __shared__ unsigned short Bs[64][56];
  const int n0 = blockIdx.x*64, m0 = blockIdx.y*64, kz = blockIdx.z;
  const float* W; const float* bias; int ldw, wc0;
  if(n0 < 2048)      { W=qw; bias=qbv; ldw=2048; wc0=n0; }
  else if(n0 < 2304) { W=kw; bias=kbv; ldw=256;  wc0=n0-2048; }
  else               { W=vw; bias=vbv; ldw=256;  wc0=n0-2304; }
  const int t = threadIdx.x, lane = t&63, wid = t>>6;
  const int wr = wid>>1, wc = wid&1, l15 = lane&15, lq = lane>>4;
  const int ar = t>>2,  ac = (t&3)*8;
  const int bk = t>>5,  bn = (t&31)*2;
  f32x4 acc[2][2] = {};
  for(int k0 = kz*1024; k0 < kz*1024 + 1024; k0 += 32){
    __syncthreads();
    *(uint4*)(&As[ar][ac]) = *(const uint4*)(A + (m0+ar)*2048 + k0 + ac);
    #pragma unroll
    for(int p=0;p<4;p++){
      const int kk = bk + p*8;
      const float2 wv = *(const float2*)(W + (long)(k0+kk)*ldw + wc0 + bn);
      Bs[bn  ][kk] = f2b(wv.x);
      Bs[bn+1][kk] = f2b(wv.y);
    }
    __syncthreads();
    const bf16x8 a0 = ld_frag(&As[wr*32      + l15][lq*8]);
    const bf16x8 a1 = ld_frag(&As[wr*32 + 16 + l15][lq*8]);
    const bf16x8 b0 = ld_frag(&Bs[wc*32      + l15][lq*8]);
    const bf16x8 b1 = ld_frag(&Bs[wc*32 + 16 + l15][lq*8]);
    acc[0][0] = mf(a0,b0,acc[0][0]);
    acc[0][1] = mf(a0,b1,acc[0][1]);
    acc[1][0] = mf(a1,b0,acc[1][0]);
    acc[1][1] = mf(a1,b1,acc[1][1]);
  }
  float* out = rawp + (long)kz*M_*NQKV;
  #pragma unroll
  for(int mi=0;mi<2;mi++)
    #pragma unroll
    for(int nj=0;nj<2;nj++){
      const int col = n0 + wc*32 + nj*16 + l15;
      const float bv = kz ? 0.f : bias[wc0 + wc*32 + nj*16 + l15];
      #pragma unroll
      for(int rr=0;rr<4;rr++){
        const int row = m0 + wr*32 + mi*16 + lq*4 + rr;
        out[row*NQKV + col] = acc[mi][nj][rr] + bv;
      }
    }
}

// ---------------- K2: sum K-halves + RoPE + pack ----------------
__global__ __launch_bounds__(128) void k_rope(
    const float* __restrict__ rawp, const float* __restrict__ cosb, const float* __restrict__ sinb,
    unsigned short* __restrict__ Qb, float* __restrict__ KnF, float* __restrict__ VnF)
{
  const int r = blockIdx.x, hh = blockIdx.y, d = threadIdx.x;
  const int b = r>>5, s = r&31;
  const float cv = cosb[(b*S_+s)*HD_ + d];
  const float sv = sinb[(b*S_+s)*HD_ + d];
  const int dp = (d<64)? d+64 : d-64;
  #define RAW2(c) (rawp[r*NQKV + (c)] + rawp[(long)M_*NQKV + r*NQKV + (c)])
  if(hh < 16){
    const float x  = RAW2(hh*HD_ + d);
    const float xo = RAW2(hh*HD_ + dp);
    const float y  = x*cv + ((d<64)? -xo : xo)*sv;
    const int kvh = hh>>3, g = hh&7;
    Qb[((long)(b*NKV_+kvh)*M_ + g*S_ + s)*HD_ + d] = f2b(y);
  } else if(hh < 18){
    const int kvh = hh-16;
    const float x  = RAW2(2048 + kvh*HD_ + d);
    const float xo = RAW2(2048 + kvh*HD_ + dp);
    KnF[((long)(b*NKV_+kvh)*S_ + s)*HD_ + d] = x*cv + ((d<64)? -xo : xo)*sv;
  } else {
    const int kvh = hh-18;
    VnF[((long)(b*NKV_+kvh)*S_ + s)*HD_ + d] = RAW2(2304 + kvh*HD_ + d);
  }
  #undef RAW2
}

// ---------------- K3: split-KV attention, 4-wave blocks, q-split ------------
// grid (sp=16, kvh*2+qh=4, b=8) = 512 blocks -> 2 co-resident blocks/CU.
// 256 thr = 4 waves; each wave 32 q rows; block = 128 q x 512 kv (8 subtiles).
__global__ __launch_bounds__(256) void k_attn(
    const unsigned short* __restrict__ Qb,
    const float* __restrict__ KnF, const float* __restrict__ VnF,
    const float* __restrict__ kc, const float* __restrict__ vc,
    const float* __restrict__ mask, const int* __restrict__ rpp,
    unsigned short* __restrict__ num, float* __restrict__ mbuf, float* __restrict__ lbuf)
{
  __shared__ __align__(16) unsigned short lds[2][2][KT_*128]; // [buf][K|Vt] 64KB
  const int sp = blockIdx.x, kvh = blockIdx.y>>1, qh = blockIdx.y&1, b = blockIdx.z;
  const int bk = b*NKV_ + kvh;
  const int rp = *rpp;
  const int t = threadIdx.x, lane = t&63, wid = t>>6;
  const int l31 = lane&31, hi = lane>>5;
  const int kvbase = sp*(KV_/NSP);
  // staging mappings (256 threads)
  const int krow = t>>2, kc0 = (t&2)? 64:0, kq = t&1;  // K: 64 rows x 2 col-halves x 2
  const int vhd  = t&127, vkq = t>>7;                  // V: 128 hd cols x 2 kv-halves

  // Q fragments, held in registers for whole block
  bf16x8 qf[8];
  { const unsigned short* qp = Qb + ((long)bk*M_ + qh*128 + wid*32 + l31)*HD_;
    #pragma unroll
    for(int ks=0;ks<8;ks++) qf[ks] = ld_frag(qp + ks*16 + hi*8); }

  float4 vK4[8];
  float  vV[32];

  auto loadK = [&](int tt){
    const int kvr = kvbase + tt*KT_ + krow;
    const float* kp = (kvr>=rp && kvr<rp+S_)
        ? (KnF + ((long)bk*S_ + (kvr-rp))*HD_ + kc0 + kq*32)
        : (kc  + ((long)bk*KV_ + kvr)*HD_ + kc0 + kq*32);
    #pragma unroll
    for(int i=0;i<8;i++) vK4[i] = *(const float4*)(kp + i*4);
  };
  auto loadV = [&](int tt){
    #pragma unroll
    for(int m=0;m<32;m++){
      const int kvr = kvbase + tt*KT_ + vkq*32 + m;   // wave-uniform row
      const float* vp = (kvr>=rp && kvr<rp+S_)
          ? (VnF + ((long)bk*S_ + (kvr-rp))*HD_)
          : (vc  + ((long)bk*KV_ + kvr)*HD_);
      vV[m] = vp[vhd];
    }
  };
  auto writeK = [&](int bb){
    unsigned short* Sb = &lds[bb][0][0];
    #pragma unroll
    for(int i=0;i<4;i++){
      uint4 w4;
      w4.x = pk2(vK4[2*i].x,   vK4[2*i].y);  w4.y = pk2(vK4[2*i].z,   vK4[2*i].w);
      w4.z = pk2(vK4[2*i+1].x, vK4[2*i+1].y);w4.w = pk2(vK4[2*i+1].z, vK4[2*i+1].w);
      *(uint4*)(Sb + swiK(krow, kc0 + kq*32 + i*8)) = w4;
    }
  };
  auto writeV = [&](int bb){
    unsigned short* Sb = &lds[bb][1][0];
    #pragma unroll
    for(int i=0;i<4;i++){
      uint4 w4;
      w4.x = pk2(vV[i*8+0], vV[i*8+1]);  w4.y = pk2(vV[i*8+2], vV[i*8+3]);
      w4.z = pk2(vV[i*8+4], vV[i*8+5]);  w4.w = pk2(vV[i*8+6], vV[i*8+7]);
      *(uint4*)(Sb + swiV(vhd, vkq*32 + i*8)) = w4;
    }
  };

  // prologue: stage subtile 0 into buf 0
  loadK(0); writeK(0); loadV(0); writeV(0);
  __syncthreads();

  f32x16 oc[4] = {};
  float m_run = -3.0e38f, l_run = 0.f;

  for(int tt=0; tt<NT_; tt++){
    const int cur = tt&1;
    if(tt<NT_-1) loadK(tt+1);                  // K loads in flight across QK^T
    // ---- QK^T: sc[kvt], kv = kvt*32 + (e&3)+8*(e>>2)+4*hi, q = l31 ----
    f32x16 sc[2] = {};
    { const unsigned short* Sk = &lds[cur][0][0];
      __builtin_amdgcn_s_setprio(1);
      #pragma unroll
      for(int ks=0;ks<8;ks++){
        #pragma unroll
        for(int kvt=0;kvt<2;kvt++)
          sc[kvt] = mf32(ld_frag(Sk + swiK(kvt*32 + l31, ks*16 + hi*8)), qf[ks], sc[kvt]);
      }
      __builtin_amdgcn_s_setprio(0);
    }
    if(tt<NT_-1){ writeK(cur^1); loadV(tt+1); }  // K regs die; V loads in flight
    // ---- mask + scale + tile max ----
    const float* mrow = mask + ((long)b*S_ + l31)*KV_ + kvbase + tt*KT_;
    float tmx = -3.0e38f;
    #pragma unroll
    for(int kvt=0;kvt<2;kvt++){
      #pragma unroll
      for(int r4=0;r4<4;r4++){
        const float4 mk = *(const float4*)(mrow + kvt*32 + r4*8 + hi*4);
        sc[kvt][r4*4+0] = sc[kvt][r4*4+0]*SCALE_ + mk.x;
        sc[kvt][r4*4+1] = sc[kvt][r4*4+1]*SCALE_ + mk.y;
        sc[kvt][r4*4+2] = sc[kvt][r4*4+2]*SCALE_ + mk.z;
        sc[kvt][r4*4+3] = sc[kvt][r4*4+3]*SCALE_ + mk.w;
        tmx = fmaxf(tmx, fmaxf(fmaxf(sc[kvt][r4*4+0], sc[kvt][r4*4+1]),
                               fmaxf(sc[kvt][r4*4+2], sc[kvt][r4*4+3])));
      }
    }
    tmx = fmaxf(tmx, __shfl_xor(tmx, 32, 64));
    // ---- T13 defer-rescale ----
    if(!__all(tmx - m_run <= 8.0f)){
      const float mx  = fmaxf(m_run, tmx);
      const float scl = __expf(m_run - mx);   // first iter: exp(-huge)=0
      #pragma unroll
      for(int r4=0;r4<4;r4++)
        #pragma unroll
        for(int rr=0;rr<4;rr++){
          const float sq = __shfl(scl, rr + 8*r4 + 4*hi, 64);
          #pragma unroll
          for(int ht=0;ht<4;ht++) oc[ht][r4*4+rr] *= sq;
        }
      l_run *= scl;
      m_run = mx;
    }
    // ---- exp + per-lane partial sum ----
    float psum = 0.f;
    #pragma unroll
    for(int kvt=0;kvt<2;kvt++)
      #pragma unroll
      for(int e=0;e<16;e++){
        const float p = __expf(sc[kvt][e] - m_run);
        sc[kvt][e] = p; psum += p;
      }
    l_run += psum;
    // ---- pack P to bf16 pairs ----
    unsigned w_[2][4][2];
    #pragma unroll
    for(int kvt=0;kvt<2;kvt++)
      #pragma unroll
      for(int r4=0;r4<4;r4++){
        w_[kvt][r4][0] = pk2(sc[kvt][r4*4+0], sc[kvt][r4*4+1]);
        w_[kvt][r4][1] = pk2(sc[kvt][r4*4+2], sc[kvt][r4*4+3]);
      }
    // ---- PV: O[q][hd] += P x V ----
    { const unsigned short* Sv = &lds[cur][1][0];
      __builtin_amdgcn_s_setprio(1);
      #pragma unroll
      for(int kvs=0;kvs<4;kvs++){
        const int kvt = kvs>>1, k2 = (kvs&1)*2;
        const unsigned wa0 = w_[kvt][k2  ][0], wa1 = w_[kvt][k2  ][1];
        const unsigned wb0 = w_[kvt][k2+1][0], wb1 = w_[kvt][k2+1][1];
        const unsigned own0 = hi? wb0:wa0, own1 = hi? wb1:wa1;
        const unsigned snd0 = hi? wa0:wb0, snd1 = hi? wa1:wb1;
        const unsigned rcv0 = __shfl_xor(snd0, 32, 64);
        const unsigned rcv1 = __shfl_xor(snd1, 32, 64);
        union{ unsigned u[4]; bf16x8 v; } ap;
        ap.u[0] = hi? rcv0:own0;  ap.u[1] = hi? rcv1:own1;
        ap.u[2] = hi? own0:rcv0;  ap.u[3] = hi? own1:rcv1;
        #pragma unroll
        for(int ht=0;ht<4;ht++)
          oc[ht] = mf32(ap.v, ld_frag(Sv + swiV(ht*32 + l31, kvs*16 + hi*8)), oc[ht]);
      }
      __builtin_amdgcn_s_setprio(0);
    }
    // ---- stage next V into other buffer ----
    if(tt<NT_-1) writeV(cur^1);
    __syncthreads();
  }

  // ---- epilogue: write partials ----
  const float l_tot = l_run + __shfl_xor(l_run, 32, 64);
  if(lane < 32){
    const long base = ((long)bk*NSP + sp)*M_ + qh*128 + wid*32 + lane;
    mbuf[base] = m_run;
    lbuf[base] = l_tot;
  }
  unsigned short* np_ = num + (((long)bk*NSP + sp)*M_ + qh*128 + wid*32)*HD_;
  #pragma unroll
  for(int ht=0;ht<4;ht++)
    #pragma unroll
    for(int r4=0;r4<4;r4++)
      #pragma unroll
      for(int rr=0;rr<4;rr++){
        const int q = rr + 8*r4 + 4*hi;
        np_[(long)q*HD_ + ht*32 + l31] = f2b(oc[ht][r4*4+rr]);
      }
}

// ---------------- K4: combine split-KV partials ----------------
__global__ __launch_bounds__(128) void k_comb(
    const unsigned short* __restrict__ num, const float* __restrict__ mbuf,
    const float* __restrict__ lbuf, unsigned short* __restrict__ attnb)
{
  const int q = blockIdx.x, kvh = blockIdx.y, b = blockIdx.z, d = threadIdx.x;
  const int bk = b*NKV_ + kvh;
  float M = -3.0e38f;
  #pragma unroll
  for(int c=0;c<NSP;c++) M = fmaxf(M, mbuf[((long)bk*NSP + c)*M_ + q]);
  float den = 0.f, acc = 0.f;
  #pragma unroll
  for(int c=0;c<NSP;c++){
    const long ix = ((long)bk*NSP + c)*M_ + q;
    const float w = __expf(mbuf[ix] - M);
    den += lbuf[ix]*w;
    acc += w * b2f(num[ix*HD_ + d]);
  }
  const int g = q>>5, s = q&31, h = kvh*G_ + g;
  attnb[((long)(b*S_+s))*2048 + h*HD_ + d] = f2b(acc/den);
}

// ---------------- K5: output projection GEMM ----------------
__global__ __launch_bounds__(256) void k_gemm_o(
    const unsigned short* __restrict__ A,
    const float* __restrict__ W,
    float* __restrict__ out)
{
  __shared__ unsigned short As[64][56];
  __shared__ unsigned short Bs[64][56];
  const int n0 = blockIdx.x*64, m0 = blockIdx.y*64;
  const int t = threadIdx.x, lane = t&63, wid = t>>6;
  const int wr = wid>>1, wc = wid&1, l15 = lane&15, lq = lane>>4;
  const int ar = t>>2,  ac = (t&3)*8;
  const int bk = t>>5,  bn = (t&31)*2;
  f32x4 acc[2][2] = {};
  for(int k0 = 0; k0 < 2048; k0 += 32){
    __syncthreads();
    *(uint4*)(&As[ar][ac]) = *(const uint4*)(A + (m0+ar)*2048 + k0 + ac);
    #pragma unroll
    for(int p=0;p<4;p++){
      const int kk = bk + p*8;
      const float2 wv = *(const float2*)(W + (long)(k0+kk)*2048 + n0 + bn);
      Bs[bn  ][kk] = f2b(wv.x);
      Bs[bn+1][kk] = f2b(wv.y);
    }
    __syncthreads();
    const bf16x8 a0 = ld_frag(&As[wr*32      + l15][lq*8]);
    const bf16x8 a1 = ld_frag(&As[wr*32 + 16 + l15][lq*8]);
    const bf16x8 b0 = ld_frag(&Bs[wc*32      + l15][lq*8]);
    const bf16x8 b1 = ld_frag(&Bs[wc*32 + 16 + l15][lq*8]);
    acc[0][0] = mf(a0,b0,acc[0][0]);
    acc[0][1] = mf(a0,b1,acc[0][1]);
    acc[1][0] = mf(a1,b0,acc[1][0]);
    acc[1][1] = mf(a1,b1,acc[1][1]);
  }
  #pragma unroll
  for(int mi=0;mi<2;mi++)
    #pragma unroll
    for(int nj=0;nj<2;nj++){
      const int col = n0 + wc*32 + nj*16 + l15;
      #pragma unroll
      for(int rr=0;rr<4;rr++){
        const int row = m0 + wr*32 + mi*16 + lq*4 + rr;
        out[row*2048 + col] = acc[mi][nj][rr];
      }
    }
}

extern "C" void kernel_launch(void* const* d_in, const int* in_sizes, int n_in,
                              void* d_out, int out_size, void* d_ws, size_t ws_size,
                              hipStream_t stream){
  (void)in_sizes; (void)n_in; (void)out_size; (void)ws_size;
  const float* hs   = (const float*)d_in[0];
  const float* cosb = (const float*)d_in[1];
  const float* sinb = (const float*)d_in[2];
  const float* kc   = (const float*)d_in[3];
  const float* vc   = (const float*)d_in[4];
  const float* mask = (const float*)d_in[5];
  const int*   rp   = (const int*)  d_in[6];
  const float* qw   = (const float*)d_in[7];
  const float* qb   = (const float*)d_in[8];
  const float* kw   = (const float*)d_in[9];
  const float* kb   = (const float*)d_in[10];
  const float* vw   = (const float*)d_in[11];
  const float* vb   = (const float*)d_in[12];
  const float* ow   = (const float*)d_in[13];
  char* ws = (char*)d_ws;
  // ws layout (bytes)
  unsigned short* hsb   = (unsigned short*)(ws + 0);          // 1,048,576
  float*          rawp  = (float*)         (ws + 1048576);    // 5,242,880 (2 K-halves)
  unsigned short* Qb    = (unsigned short*)(ws + 6291456);    // 1,048,576
  float*          KnF   = (float*)         (ws + 7340032);    //   262,144
  float*          VnF   = (float*)         (ws + 7602176);    //   262,144
  unsigned short* attnb = (unsigned short*)(ws + 7864320);    // 1,048,576
  float*          mbuf  = (float*)         (ws + 8912896);    //   262,144
  float*          lbuf  = (float*)         (ws + 9175040);    //   262,144
  unsigned short* num   = (unsigned short*)(ws + 9437184);    // 16,777,216  (end ~26.2 MB)
  float* outp = (float*)d_out;

  k_cvt     <<<dim3(512),        dim3(256), 0, stream>>>(hs, hsb);
  k_gemm_qkv<<<dim3(40,4,2),     dim3(256), 0, stream>>>(hsb, qw,kw,vw, qb,kb,vb, rawp);
  k_rope    <<<dim3(256,20),     dim3(128), 0, stream>>>(rawp, cosb, sinb, Qb, KnF, VnF);
  k_attn    <<<dim3(NSP,4,8),    dim3(256), 0, stream>>>(Qb, KnF, VnF, kc, vc, mask, rp, num, mbuf, lbuf);
  k_comb    <<<dim3(256,2,8),    dim3(128), 0, stream>>>(num, mbuf, lbuf, attnb);
  k_gemm_o  <<<dim3(32,4),       dim3(256), 0, stream>>>(attnb, ow, outp);
}

// Round 7
// 158.836 us; speedup vs baseline: 2.2313x; 1.2574x over previous
//
#include <hip/hip_runtime.h>
#include <hip/hip_bf16.h>

#define B_    8
#define S_    32
#define H_    2048
#define NH_   16
#define NKV_  2
#define HD_   128
#define KV_   8192
#define G_    8
#define M_    256      /* B*S */
#define NQKV  2560     /* fused proj N: 2048 q | 256 k | 256 v */
#define NSP   16       /* kv splits */
#define KT_   64       /* kv subtile */
#define NT_   8        /* subtiles per block = KV_/NSP/KT_ */
#define SCALE_ 0.08838834764831845f

typedef __bf16 bf16x8 __attribute__((ext_vector_type(8)));
typedef float  f32x4  __attribute__((ext_vector_type(4)));

__device__ __forceinline__ unsigned short f2b(float f){
  unsigned u = __float_as_uint(f);
  u = u + 0x7FFFu + ((u>>16)&1u);           // RNE f32->bf16
  return (unsigned short)(u>>16);
}
__device__ __forceinline__ float b2f(unsigned short h){
  return __uint_as_float(((unsigned)h)<<16);
}
__device__ __forceinline__ unsigned pk2(float a, float b){
  return (unsigned)f2b(a) | ((unsigned)f2b(b)<<16);
}
__device__ __forceinline__ bf16x8 ld_frag(const unsigned short* p){
  union { uint4 u; bf16x8 b; } cv;
  cv.u = *(const uint4*)p;
  return cv.b;
}
__device__ __forceinline__ f32x4 mf(bf16x8 a, bf16x8 b, f32x4 c){
  return __builtin_amdgcn_mfma_f32_16x16x32_bf16(a, b, c, 0, 0, 0);
}
// K tile swizzle: 64 rows x 128 cols (shorts), 16B-group XOR
__device__ __forceinline__ int swiK(int row, int col){
  return row*128 + (col ^ ((((row)&15) ^ ((row>>1)&8)) << 3));
}
// Vt tile swizzle: 128 rows x 64 cols (shorts)
__device__ __forceinline__ int swiV(int row, int col){
  return row*64 + (col ^ (((row)&7) << 3));
}

// ---------------- K0: hidden_states f32 -> bf16 ----------------
__global__ __launch_bounds__(256) void k_cvt(const float* __restrict__ x,
                                             unsigned short* __restrict__ y){
  const int i = (blockIdx.x*256 + threadIdx.x)*4;
  const float4 v = *(const float4*)(x + i);
  ushort4 o; o.x=f2b(v.x); o.y=f2b(v.y); o.z=f2b(v.z); o.w=f2b(v.w);
  *(ushort4*)(y + i) = o;
}

// ---------------- K1: fused QKV projection GEMM, split-K=2 ----------------
__global__ __launch_bounds__(256) void k_gemm_qkv(
    const unsigned short* __restrict__ A,
    const float* __restrict__ qw, const float* __restrict__ kw, const float* __restrict__ vw,
    const float* __restrict__ qbv, const float* __restrict__ kbv, const float* __restrict__ vbv,
    float* __restrict__ rawp)
{
  __shared__ unsigned short As[64][56];
  __shared__ unsigned short Bs[64][56];
  const int n0 = blockIdx.x*64, m0 = blockIdx.y*64, kz = blockIdx.z;
  const float* W; const float* bias; int ldw, wc0;
  if(n0 < 2048)      { W=qw; bias=qbv; ldw=2048; wc0=n0; }
  else if(n0 < 2304) { W=kw; bias=kbv; ldw=256;  wc0=n0-2048; }
  else               { W=vw; bias=vbv; ldw=256;  wc0=n0-2304; }
  const int t = threadIdx.x, lane = t&63, wid = t>>6;
  const int wr = wid>>1, wc = wid&1, l15 = lane&15, lq = lane>>4;
  const int ar = t>>2,  ac = (t&3)*8;
  const int bk = t>>5,  bn = (t&31)*2;
  f32x4 acc[2][2] = {};
  for(int k0 = kz*1024; k0 < kz*1024 + 1024; k0 += 32){
    __syncthreads();
    *(uint4*)(&As[ar][ac]) = *(const uint4*)(A + (m0+ar)*2048 + k0 + ac);
    #pragma unroll
    for(int p=0;p<4;p++){
      const int kk = bk + p*8;
      const float2 wv = *(const float2*)(W + (long)(k0+kk)*ldw + wc0 + bn);
      Bs[bn  ][kk] = f2b(wv.x);
      Bs[bn+1][kk] = f2b(wv.y);
    }
    __syncthreads();
    const bf16x8 a0 = ld_frag(&As[wr*32      + l15][lq*8]);
    const bf16x8 a1 = ld_frag(&As[wr*32 + 16 + l15][lq*8]);
    const bf16x8 b0 = ld_frag(&Bs[wc*32      + l15][lq*8]);
    const bf16x8 b1 = ld_frag(&Bs[wc*32 + 16 + l15][lq*8]);
    acc[0][0] = mf(a0,b0,acc[0][0]);
    acc[0][1] = mf(a0,b1,acc[0][1]);
    acc[1][0] = mf(a1,b0,acc[1][0]);
    acc[1][1] = mf(a1,b1,acc[1][1]);
  }
  float* out = rawp + (long)kz*M_*NQKV;
  #pragma unroll
  for(int mi=0;mi<2;mi++)
    #pragma unroll
    for(int nj=0;nj<2;nj++){
      const int col = n0 + wc*32 + nj*16 + l15;
      const float bv = kz ? 0.f : bias[wc0 + wc*32 + nj*16 + l15];
      #pragma unroll
      for(int rr=0;rr<4;rr++){
        const int row = m0 + wr*32 + mi*16 + lq*4 + rr;
        out[row*NQKV + col] = acc[mi][nj][rr] + bv;
      }
    }
}

// ---------------- K2: sum K-halves + RoPE + pack ----------------
__global__ __launch_bounds__(128) void k_rope(
    const float* __restrict__ rawp, const float* __restrict__ cosb, const float* __restrict__ sinb,
    unsigned short* __restrict__ Qb, float* __restrict__ KnF, float* __restrict__ VnF)
{
  const int r = blockIdx.x, hh = blockIdx.y, d = threadIdx.x;
  const int b = r>>5, s = r&31;
  const float cv = cosb[(b*S_+s)*HD_ + d];
  const float sv = sinb[(b*S_+s)*HD_ + d];
  const int dp = (d<64)? d+64 : d-64;
  #define RAW2(c) (rawp[r*NQKV + (c)] + rawp[(long)M_*NQKV + r*NQKV + (c)])
  if(hh < 16){
    const float x  = RAW2(hh*HD_ + d);
    const float xo = RAW2(hh*HD_ + dp);
    const float y  = x*cv + ((d<64)? -xo : xo)*sv;
    const int kvh = hh>>3, g = hh&7;
    Qb[((long)(b*NKV_+kvh)*M_ + g*S_ + s)*HD_ + d] = f2b(y);
  } else if(hh < 18){
    const int kvh = hh-16;
    const float x  = RAW2(2048 + kvh*HD_ + d);
    const float xo = RAW2(2048 + kvh*HD_ + dp);
    KnF[((long)(b*NKV_+kvh)*S_ + s)*HD_ + d] = x*cv + ((d<64)? -xo : xo)*sv;
  } else {
    const int kvh = hh-18;
    VnF[((long)(b*NKV_+kvh)*S_ + s)*HD_ + d] = RAW2(2304 + kvh*HD_ + d);
  }
  #undef RAW2
}

// ---------------- K3: split-KV attention, 16 q/wave, 16x16x32 MFMA ----------
// grid (sp=16, kvh*2+qh=4, b=8) = 512 blocks -> 2 blocks/CU (16 waves/CU).
// 512 thr = 8 waves; each wave 16 q rows; block = 128 q x 512 kv (8 subtiles).
__global__ __launch_bounds__(512, 4) void k_attn(
    const unsigned short* __restrict__ Qb,
    const float* __restrict__ KnF, const float* __restrict__ VnF,
    const float* __restrict__ kc, const float* __restrict__ vc,
    const float* __restrict__ mask, const int* __restrict__ rpp,
    unsigned short* __restrict__ num, float* __restrict__ mbuf, float* __restrict__ lbuf)
{
  __shared__ __align__(16) unsigned short lds[2][2][KT_*128]; // [buf][K|Vt] 64KB
  const int sp = blockIdx.x, kvh = blockIdx.y>>1, qh = blockIdx.y&1, b = blockIdx.z;
  const int bk = b*NKV_ + kvh;
  const int rp = *rpp;
  const int t = threadIdx.x, lane = t&63, wid = t>>6;
  const int l15 = lane&15, lq = lane>>4;
  const int kvbase = sp*(KV_/NSP);
  // staging mappings (512 threads)
  const int krow = t>>3, kc0 = (t&7)*16;  // K: 64 rows x 8 col-eighths (16 f32)
  const int vhd  = t&127, vkq = t>>7;     // V: 128 hd cols x 4 kv-quarters (16 rows)

  // Q fragments (wave's 16 q rows; lane: q=l15, k=ks*32+lq*8)
  bf16x8 qf[4];
  { const unsigned short* qp = Qb + ((long)bk*M_ + qh*128 + wid*16 + l15)*HD_;
    #pragma unroll
    for(int ks=0;ks<4;ks++) qf[ks] = ld_frag(qp + ks*32 + lq*8); }

  float4 vK4[4];
  float  vV[16];

  auto loadK = [&](int tt){
    const int kvr = kvbase + tt*KT_ + krow;
    const float* kp = (kvr>=rp && kvr<rp+S_)
        ? (KnF + ((long)bk*S_ + (kvr-rp))*HD_ + kc0)
        : (kc  + ((long)bk*KV_ + kvr)*HD_ + kc0);
    #pragma unroll
    for(int i=0;i<4;i++) vK4[i] = *(const float4*)(kp + i*4);
  };
  auto loadV = [&](int tt){
    #pragma unroll
    for(int m=0;m<16;m++){
      const int kvr = kvbase + tt*KT_ + vkq*16 + m;   // wave-uniform row
      const float* vp = (kvr>=rp && kvr<rp+S_)
          ? (VnF + ((long)bk*S_ + (kvr-rp))*HD_)
          : (vc  + ((long)bk*KV_ + kvr)*HD_);
      vV[m] = vp[vhd];
    }
  };
  auto writeK = [&](int bb){
    unsigned short* Sb = &lds[bb][0][0];
    uint4 w4;
    w4.x = pk2(vK4[0].x, vK4[0].y);  w4.y = pk2(vK4[0].z, vK4[0].w);
    w4.z = pk2(vK4[1].x, vK4[1].y);  w4.w = pk2(vK4[1].z, vK4[1].w);
    *(uint4*)(Sb + swiK(krow, kc0)) = w4;
    w4.x = pk2(vK4[2].x, vK4[2].y);  w4.y = pk2(vK4[2].z, vK4[2].w);
    w4.z = pk2(vK4[3].x, vK4[3].y);  w4.w = pk2(vK4[3].z, vK4[3].w);
    *(uint4*)(Sb + swiK(krow, kc0 + 8)) = w4;
  };
  auto writeV = [&](int bb){
    unsigned short* Sb = &lds[bb][1][0];
    uint4 w4;
    w4.x = pk2(vV[0], vV[1]);   w4.y = pk2(vV[2], vV[3]);
    w4.z = pk2(vV[4], vV[5]);   w4.w = pk2(vV[6], vV[7]);
    *(uint4*)(Sb + swiV(vhd, vkq*16)) = w4;
    w4.x = pk2(vV[8], vV[9]);   w4.y = pk2(vV[10], vV[11]);
    w4.z = pk2(vV[12], vV[13]); w4.w = pk2(vV[14], vV[15]);
    *(uint4*)(Sb + swiV(vhd, vkq*16 + 8)) = w4;
  };

  // prologue: stage subtile 0 into buf 0
  loadK(0); writeK(0); loadV(0); writeV(0);
  __syncthreads();

  f32x4 oc[8] = {};
  float m_run = -3.0e38f, l_run = 0.f;

  for(int tt=0; tt<NT_; tt++){
    const int cur = tt&1;
    if(tt<NT_-1) loadK(tt+1);                  // next K in flight across QK^T
    // ---- QK^T: sc[kt] = D[kv16][q16]; lane q=l15, kv=kt*16+lq*4+r ----
    f32x4 sc[4] = {};
    { const unsigned short* Sk = &lds[cur][0][0];
      __builtin_amdgcn_s_setprio(1);
      #pragma unroll
      for(int ks=0;ks<4;ks++){
        #pragma unroll
        for(int kt=0;kt<4;kt++)
          sc[kt] = mf(ld_frag(Sk + swiK(kt*16 + l15, ks*32 + lq*8)), qf[ks], sc[kt]);
      }
      __builtin_amdgcn_s_setprio(0);
    }
    if(tt<NT_-1){ writeK(cur^1); loadV(tt+1); }  // K regs die; V loads in flight
    // ---- mask + scale + tile max ----
    const float* mrow = mask + ((long)b*S_ + ((wid*16 + l15)&31))*KV_ + kvbase + tt*KT_;
    float tmx = -3.0e38f;
    #pragma unroll
    for(int kt=0;kt<4;kt++){
      const float4 mk = *(const float4*)(mrow + kt*16 + lq*4);
      sc[kt][0] = sc[kt][0]*SCALE_ + mk.x;
      sc[kt][1] = sc[kt][1]*SCALE_ + mk.y;
      sc[kt][2] = sc[kt][2]*SCALE_ + mk.z;
      sc[kt][3] = sc[kt][3]*SCALE_ + mk.w;
      tmx = fmaxf(tmx, fmaxf(fmaxf(sc[kt][0], sc[kt][1]), fmaxf(sc[kt][2], sc[kt][3])));
    }
    tmx = fmaxf(tmx, __shfl_xor(tmx, 16, 64));
    tmx = fmaxf(tmx, __shfl_xor(tmx, 32, 64));
    // ---- T13 defer-rescale ----
    if(!__all(tmx - m_run <= 8.0f)){
      const float mx  = fmaxf(m_run, tmx);
      const float scl = __expf(m_run - mx);   // first iter: exp(-huge)=0
      #pragma unroll
      for(int rr=0;rr<4;rr++){
        const float sq = __shfl(scl, (lane>>4)*4 + rr, 64);  // scl for q'=lq*4+rr
        #pragma unroll
        for(int ht=0;ht<8;ht++) oc[ht][rr] *= sq;
      }
      l_run *= scl;
      m_run = mx;
    }
    // ---- exp + per-lane partial sum (16 kv values per lane) ----
    float psum = 0.f;
    #pragma unroll
    for(int kt=0;kt<4;kt++)
      #pragma unroll
      for(int e=0;e<4;e++){
        const float p = __expf(sc[kt][e] - m_run);
        sc[kt][e] = p; psum += p;
      }
    l_run += psum;
    // ---- pack P (q=l15, kv=kt*16+lq*4+r) to bf16 pairs ----
    unsigned w_[4][2];
    #pragma unroll
    for(int kt=0;kt<4;kt++){
      w_[kt][0] = pk2(sc[kt][0], sc[kt][1]);
      w_[kt][1] = pk2(sc[kt][2], sc[kt][3]);
    }
    // ---- redistribute P into A-frags: pa[b] covers kv=b*32+lq*8+e ----
    const int src0 = l15 + ((lq&1)<<5);      // source lane group (lq&1)*2
    const int src1 = src0 + 16;              // source lane group (lq&1)*2+1
    unsigned a_[4][4];
    #pragma unroll
    for(int kt=0;kt<4;kt++){
      a_[kt][0] = __shfl(w_[kt][0], src0, 64);
      a_[kt][1] = __shfl(w_[kt][1], src0, 64);
      a_[kt][2] = __shfl(w_[kt][0], src1, 64);
      a_[kt][3] = __shfl(w_[kt][1], src1, 64);
    }
    const bool hiKt = ((lq>>1)&1);           // frag b uses kt=2b+(lq>>1)
    union{ unsigned u[4]; bf16x8 v; } pa0, pa1;
    #pragma unroll
    for(int j=0;j<4;j++){
      pa0.u[j] = hiKt ? a_[1][j] : a_[0][j];
      pa1.u[j] = hiKt ? a_[3][j] : a_[2][j];
    }
    // ---- PV: oc[ht] D[q16][hd16]; lane hd=l15, q=lq*4+r ----
    { const unsigned short* Sv = &lds[cur][1][0];
      __builtin_amdgcn_s_setprio(1);
      #pragma unroll
      for(int ht=0;ht<8;ht++){
        oc[ht] = mf(pa0.v, ld_frag(Sv + swiV(ht*16 + l15,      lq*8)), oc[ht]);
        oc[ht] = mf(pa1.v, ld_frag(Sv + swiV(ht*16 + l15, 32 + lq*8)), oc[ht]);
      }
      __builtin_amdgcn_s_setprio(0);
    }
    // ---- stage next V into other buffer ----
    if(tt<NT_-1) writeV(cur^1);
    __syncthreads();
  }

  // ---- epilogue: write partials ----
  float l_tot = l_run + __shfl_xor(l_run, 16, 64);
  l_tot += __shfl_xor(l_tot, 32, 64);
  if(lane < 16){
    const long base = ((long)bk*NSP + sp)*M_ + qh*128 + wid*16 + lane;
    mbuf[base] = m_run;
    lbuf[base] = l_tot;
  }
  unsigned short* np_ = num + (((long)bk*NSP + sp)*M_ + qh*128 + wid*16)*HD_;
  #pragma unroll
  for(int ht=0;ht<8;ht++)
    #pragma unroll
    for(int rr=0;rr<4;rr++)
      np_[(long)(lq*4+rr)*HD_ + ht*16 + l15] = f2b(oc[ht][rr]);
}

// ---------------- K4: combine split-KV partials ----------------
__global__ __launch_bounds__(128) void k_comb(
    const unsigned short* __restrict__ num, const float* __restrict__ mbuf,
    const float* __restrict__ lbuf, unsigned short* __restrict__ attnb)
{
  const int q = blockIdx.x, kvh = blockIdx.y, b = blockIdx.z, d = threadIdx.x;
  const int bk = b*NKV_ + kvh;
  float M = -3.0e38f;
  #pragma unroll
  for(int c=0;c<NSP;c++) M = fmaxf(M, mbuf[((long)bk*NSP + c)*M_ + q]);
  float den = 0.f, acc = 0.f;
  #pragma unroll
  for(int c=0;c<NSP;c++){
    const long ix = ((long)bk*NSP + c)*M_ + q;
    const float w = __expf(mbuf[ix] - M);
    den += lbuf[ix]*w;
    acc += w * b2f(num[ix*HD_ + d]);
  }
  const int g = q>>5, s = q&31, h = kvh*G_ + g;
  attnb[((long)(b*S_+s))*2048 + h*HD_ + d] = f2b(acc/den);
}

// ---------------- K5: output projection GEMM ----------------
__global__ __launch_bounds__(256) void k_gemm_o(
    const unsigned short* __restrict__ A,
    const float* __restrict__ W,
    float* __restrict__ out)
{
  __shared__ unsigned short As[64][56];
  __shared__ unsigned short Bs[64][56];
  const int n0 = blockIdx.x*64, m0 = blockIdx.y*64;
  const int t = threadIdx.x, lane = t&63, wid = t>>6;
  const int wr = wid>>1, wc = wid&1, l15 = lane&15, lq = lane>>4;
  const int ar = t>>2,  ac = (t&3)*8;
  const int bk = t>>5,  bn = (t&31)*2;
  f32x4 acc[2][2] = {};
  for(int k0 = 0; k0 < 2048; k0 += 32){
    __syncthreads();
    *(uint4*)(&As[ar][ac]) = *(const uint4*)(A + (m0+ar)*2048 + k0 + ac);
    #pragma unroll
    for(int p=0;p<4;p++){
      const int kk = bk + p*8;
      const float2 wv = *(const float2*)(W + (long)(k0+kk)*2048 + n0 + bn);
      Bs[bn  ][kk] = f2b(wv.x);
      Bs[bn+1][kk] = f2b(wv.y);
    }
    __syncthreads();
    const bf16x8 a0 = ld_frag(&As[wr*32      + l15][lq*8]);
    const bf16x8 a1 = ld_frag(&As[wr*32 + 16 + l15][lq*8]);
    const bf16x8 b0 = ld_frag(&Bs[wc*32      + l15][lq*8]);
    const bf16x8 b1 = ld_frag(&Bs[wc*32 + 16 + l15][lq*8]);
    acc[0][0] = mf(a0,b0,acc[0][0]);
    acc[0][1] = mf(a0,b1,acc[0][1]);
    acc[1][0] = mf(a1,b0,acc[1][0]);
    acc[1][1] = mf(a1,b1,acc[1][1]);
  }
  #pragma unroll
  for(int mi=0;mi<2;mi++)
    #pragma unroll
    for(int nj=0;nj<2;nj++){
      const int col = n0 + wc*32 + nj*16 + l15;
      #pragma unroll
      for(int rr=0;rr<4;rr++){
        const int row = m0 + wr*32 + mi*16 + lq*4 + rr;
        out[row*2048 + col] = acc[mi][nj][rr];
      }
    }
}

extern "C" void kernel_launch(void* const* d_in, const int* in_sizes, int n_in,
                              void* d_out, int out_size, void* d_ws, size_t ws_size,
                              hipStream_t stream){
  (void)in_sizes; (void)n_in; (void)out_size; (void)ws_size;
  const float* hs   = (const float*)d_in[0];
  const float* cosb = (const float*)d_in[1];
  const float* sinb = (const float*)d_in[2];
  const float* kc   = (const float*)d_in[3];
  const float* vc   = (const float*)d_in[4];
  const float* mask = (const float*)d_in[5];
  const int*   rp   = (const int*)  d_in[6];
  const float* qw   = (const float*)d_in[7];
  const float* qb   = (const float*)d_in[8];
  const float* kw   = (const float*)d_in[9];
  const float* kb   = (const float*)d_in[10];
  const float* vw   = (const float*)d_in[11];
  const float* vb   = (const float*)d_in[12];
  const float* ow   = (const float*)d_in[13];
  char* ws = (char*)d_ws;
  // ws layout (bytes)
  unsigned short* hsb   = (unsigned short*)(ws + 0);          // 1,048,576
  float*          rawp  = (float*)         (ws + 1048576);    // 5,242,880 (2 K-halves)
  unsigned short* Qb    = (unsigned short*)(ws + 6291456);    // 1,048,576
  float*          KnF   = (float*)         (ws + 7340032);    //   262,144
  float*          VnF   = (float*)         (ws + 7602176);    //   262,144
  unsigned short* attnb = (unsigned short*)(ws + 7864320);    // 1,048,576
  float*          mbuf  = (float*)         (ws + 8912896);    //   262,144
  float*          lbuf  = (float*)         (ws + 9175040);    //   262,144
  unsigned short* num   = (unsigned short*)(ws + 9437184);    // 16,777,216  (end ~26.2 MB)
  float* outp = (float*)d_out;

  k_cvt     <<<dim3(512),        dim3(256), 0, stream>>>(hs, hsb);
  k_gemm_qkv<<<dim3(40,4,2),     dim3(256), 0, stream>>>(hsb, qw,kw,vw, qb,kb,vb, rawp);
  k_rope    <<<dim3(256,20),     dim3(128), 0, stream>>>(rawp, cosb, sinb, Qb, KnF, VnF);
  k_attn    <<<dim3(NSP,4,8),    dim3(512), 0, stream>>>(Qb, KnF, VnF, kc, vc, mask, rp, num, mbuf, lbuf);
  k_comb    <<<dim3(256,2,8),    dim3(128), 0, stream>>>(num, mbuf, lbuf, attnb);
  k_gemm_o  <<<dim3(32,4),       dim3(256), 0, stream>>>(attnb, ow, outp);
}

// Round 8
// 151.092 us; speedup vs baseline: 2.3456x; 1.0513x over previous
//
#include <hip/hip_runtime.h>
#include <hip/hip_bf16.h>

#define B_    8
#define S_    32
#define H_    2048
#define NH_   16
#define NKV_  2
#define HD_   128
#define KV_   8192
#define G_    8
#define M_    256      /* B*S */
#define NQKV  2560     /* fused proj N: 2048 q | 256 k | 256 v */
#define NSP   16       /* kv splits */
#define KT_   64       /* kv subtile */
#define NT_   8        /* subtiles per block = KV_/NSP/KT_ */
#define SCALE_ 0.08838834764831845f

typedef __bf16 bf16x8 __attribute__((ext_vector_type(8)));
typedef float  f32x4  __attribute__((ext_vector_type(4)));

__device__ __forceinline__ unsigned short f2b(float f){
  unsigned u = __float_as_uint(f);
  u = u + 0x7FFFu + ((u>>16)&1u);           // RNE f32->bf16
  return (unsigned short)(u>>16);
}
__device__ __forceinline__ float b2f(unsigned short h){
  return __uint_as_float(((unsigned)h)<<16);
}
__device__ __forceinline__ unsigned pk2(float a, float b){
  return (unsigned)f2b(a) | ((unsigned)f2b(b)<<16);
}
__device__ __forceinline__ bf16x8 ld_frag(const unsigned short* p){
  union { uint4 u; bf16x8 b; } cv;
  cv.u = *(const uint4*)p;
  return cv.b;
}
__device__ __forceinline__ f32x4 mf(bf16x8 a, bf16x8 b, f32x4 c){
  return __builtin_amdgcn_mfma_f32_16x16x32_bf16(a, b, c, 0, 0, 0);
}
// K tile swizzle: 64 rows x 128 cols (shorts), 16B-group XOR
__device__ __forceinline__ int swiK(int row, int col){
  return row*128 + (col ^ ((((row)&15) ^ ((row>>1)&8)) << 3));
}
// Vt tile swizzle: 128 rows x 64 cols (shorts)
__device__ __forceinline__ int swiV(int row, int col){
  return row*64 + (col ^ (((row)&7) << 3));
}

// ---------------- K0: hidden_states f32 -> bf16 ----------------
__global__ __launch_bounds__(256) void k_cvt(const float* __restrict__ x,
                                             unsigned short* __restrict__ y){
  const int i = (blockIdx.x*256 + threadIdx.x)*4;
  const float4 v = *(const float4*)(x + i);
  ushort4 o; o.x=f2b(v.x); o.y=f2b(v.y); o.z=f2b(v.z); o.w=f2b(v.w);
  *(ushort4*)(y + i) = o;
}

// ---------------- K1: fused QKV projection GEMM, split-K=2 ----------------
__global__ __launch_bounds__(256) void k_gemm_qkv(
    const unsigned short* __restrict__ A,
    const float* __restrict__ qw, const float* __restrict__ kw, const float* __restrict__ vw,
    const float* __restrict__ qbv, const float* __restrict__ kbv, const float* __restrict__ vbv,
    float* __restrict__ rawp)
{
  __shared__ unsigned short As[64][56];
  __shared__ unsigned short Bs[64][56];
  const int n0 = blockIdx.x*64, m0 = blockIdx.y*64, kz = blockIdx.z;
  const float* W; const float* bias; int ldw, wc0;
  if(n0 < 2048)      { W=qw; bias=qbv; ldw=2048; wc0=n0; }
  else if(n0 < 2304) { W=kw; bias=kbv; ldw=256;  wc0=n0-2048; }
  else               { W=vw; bias=vbv; ldw=256;  wc0=n0-2304; }
  const int t = threadIdx.x, lane = t&63, wid = t>>6;
  const int wr = wid>>1, wc = wid&1, l15 = lane&15, lq = lane>>4;
  const int ar = t>>2,  ac = (t&3)*8;
  const int bk = t>>5,  bn = (t&31)*2;
  f32x4 acc[2][2] = {};
  for(int k0 = kz*1024; k0 < kz*1024 + 1024; k0 += 32){
    __syncthreads();
    *(uint4*)(&As[ar][ac]) = *(const uint4*)(A + (m0+ar)*2048 + k0 + ac);
    #pragma unroll
    for(int p=0;p<4;p++){
      const int kk = bk + p*8;
      const float2 wv = *(const float2*)(W + (long)(k0+kk)*ldw + wc0 + bn);
      Bs[bn  ][kk] = f2b(wv.x);
      Bs[bn+1][kk] = f2b(wv.y);
    }
    __syncthreads();
    const bf16x8 a0 = ld_frag(&As[wr*32      + l15][lq*8]);
    const bf16x8 a1 = ld_frag(&As[wr*32 + 16 + l15][lq*8]);
    const bf16x8 b0 = ld_frag(&Bs[wc*32      + l15][lq*8]);
    const bf16x8 b1 = ld_frag(&Bs[wc*32 + 16 + l15][lq*8]);
    acc[0][0] = mf(a0,b0,acc[0][0]);
    acc[0][1] = mf(a0,b1,acc[0][1]);
    acc[1][0] = mf(a1,b0,acc[1][0]);
    acc[1][1] = mf(a1,b1,acc[1][1]);
  }
  float* out = rawp + (long)kz*M_*NQKV;
  #pragma unroll
  for(int mi=0;mi<2;mi++)
    #pragma unroll
    for(int nj=0;nj<2;nj++){
      const int col = n0 + wc*32 + nj*16 + l15;
      const float bv = kz ? 0.f : bias[wc0 + wc*32 + nj*16 + l15];
      #pragma unroll
      for(int rr=0;rr<4;rr++){
        const int row = m0 + wr*32 + mi*16 + lq*4 + rr;
        out[row*NQKV + col] = acc[mi][nj][rr] + bv;
      }
    }
}

// ---------------- K2: sum K-halves + RoPE + pack ----------------
__global__ __launch_bounds__(128) void k_rope(
    const float* __restrict__ rawp, const float* __restrict__ cosb, const float* __restrict__ sinb,
    unsigned short* __restrict__ Qb, float* __restrict__ KnF, float* __restrict__ VnF)
{
  const int r = blockIdx.x, hh = blockIdx.y, d = threadIdx.x;
  const int b = r>>5, s = r&31;
  const float cv = cosb[(b*S_+s)*HD_ + d];
  const float sv = sinb[(b*S_+s)*HD_ + d];
  const int dp = (d<64)? d+64 : d-64;
  #define RAW2(c) (rawp[r*NQKV + (c)] + rawp[(long)M_*NQKV + r*NQKV + (c)])
  if(hh < 16){
    const float x  = RAW2(hh*HD_ + d);
    const float xo = RAW2(hh*HD_ + dp);
    const float y  = x*cv + ((d<64)? -xo : xo)*sv;
    const int kvh = hh>>3, g = hh&7;
    Qb[((long)(b*NKV_+kvh)*M_ + g*S_ + s)*HD_ + d] = f2b(y);
  } else if(hh < 18){
    const int kvh = hh-16;
    const float x  = RAW2(2048 + kvh*HD_ + d);
    const float xo = RAW2(2048 + kvh*HD_ + dp);
    KnF[((long)(b*NKV_+kvh)*S_ + s)*HD_ + d] = x*cv + ((d<64)? -xo : xo)*sv;
  } else {
    const int kvh = hh-18;
    VnF[((long)(b*NKV_+kvh)*S_ + s)*HD_ + d] = RAW2(2304 + kvh*HD_ + d);
  }
  #undef RAW2
}

// ---------------- K3: split-KV attention, 1024 thr, 256 q x 512 kv ----------
// grid (sp=16, kvh=2, b=8) = 256 blocks -> 1 block/CU, 16 waves/CU.
// 16 waves; each wave 16 q rows (16x16x32 MFMA); kv-tile staged ONCE per block.
__global__ __launch_bounds__(1024, 4) void k_attn(
    const unsigned short* __restrict__ Qb,
    const float* __restrict__ KnF, const float* __restrict__ VnF,
    const float* __restrict__ kc, const float* __restrict__ vc,
    const float* __restrict__ mask, const int* __restrict__ rpp,
    unsigned short* __restrict__ num, float* __restrict__ mbuf, float* __restrict__ lbuf)
{
  __shared__ __align__(16) unsigned short lds[2][2][KT_*128]; // [buf][K|Vt] 64KB
  const int sp = blockIdx.x, kvh = blockIdx.y, b = blockIdx.z;
  const int bk = b*NKV_ + kvh;
  const int rp = *rpp;
  const int t = threadIdx.x, lane = t&63, wid = t>>6;   // wid 0..15
  const int l15 = lane&15, lq = lane>>4;
  const int kvbase = sp*(KV_/NSP);
  // staging mappings (1024 threads, each stages 8 K f32 + 8 V f32)
  const int krow = t>>4, kc0 = (t&15)*8;  // K: 64 rows x 16 col-eighths (8 f32)
  const int vhd  = t&127, vkq = t>>7;     // V: 128 hd cols x 8 kv-eighths (8 rows)

  // Q fragments (wave's 16 q rows; lane: q=l15, k=ks*32+lq*8)
  bf16x8 qf[4];
  { const unsigned short* qp = Qb + ((long)bk*M_ + wid*16 + l15)*HD_;
    #pragma unroll
    for(int ks=0;ks<4;ks++) qf[ks] = ld_frag(qp + ks*32 + lq*8); }

  float4 vK4[2];
  float  vV[8];

  auto loadK = [&](int tt){
    const int kvr = kvbase + tt*KT_ + krow;
    const float* kp = (kvr>=rp && kvr<rp+S_)
        ? (KnF + ((long)bk*S_ + (kvr-rp))*HD_ + kc0)
        : (kc  + ((long)bk*KV_ + kvr)*HD_ + kc0);
    vK4[0] = *(const float4*)(kp);
    vK4[1] = *(const float4*)(kp + 4);
  };
  auto loadV = [&](int tt){
    #pragma unroll
    for(int m=0;m<8;m++){
      const int kvr = kvbase + tt*KT_ + vkq*8 + m;   // wave-uniform row
      const float* vp = (kvr>=rp && kvr<rp+S_)
          ? (VnF + ((long)bk*S_ + (kvr-rp))*HD_)
          : (vc  + ((long)bk*KV_ + kvr)*HD_);
      vV[m] = vp[vhd];
    }
  };
  auto writeK = [&](int bb){
    unsigned short* Sb = &lds[bb][0][0];
    uint4 w4;
    w4.x = pk2(vK4[0].x, vK4[0].y);  w4.y = pk2(vK4[0].z, vK4[0].w);
    w4.z = pk2(vK4[1].x, vK4[1].y);  w4.w = pk2(vK4[1].z, vK4[1].w);
    *(uint4*)(Sb + swiK(krow, kc0)) = w4;
  };
  auto writeV = [&](int bb){
    unsigned short* Sb = &lds[bb][1][0];
    uint4 w4;
    w4.x = pk2(vV[0], vV[1]);   w4.y = pk2(vV[2], vV[3]);
    w4.z = pk2(vV[4], vV[5]);   w4.w = pk2(vV[6], vV[7]);
    *(uint4*)(Sb + swiV(vhd, vkq*8)) = w4;
  };

  // prologue: stage subtile 0 into buf 0
  loadK(0); writeK(0); loadV(0); writeV(0);
  __syncthreads();

  f32x4 oc[8] = {};
  float m_run = -3.0e38f, l_run = 0.f;

  for(int tt=0; tt<NT_; tt++){
    const int cur = tt&1;
    if(tt<NT_-1) loadK(tt+1);                  // next K in flight across QK^T
    // ---- QK^T: sc[kt] = D[kv16][q16]; lane q=l15, kv=kt*16+lq*4+r ----
    f32x4 sc[4] = {};
    { const unsigned short* Sk = &lds[cur][0][0];
      __builtin_amdgcn_s_setprio(1);
      #pragma unroll
      for(int ks=0;ks<4;ks++){
        #pragma unroll
        for(int kt=0;kt<4;kt++)
          sc[kt] = mf(ld_frag(Sk + swiK(kt*16 + l15, ks*32 + lq*8)), qf[ks], sc[kt]);
      }
      __builtin_amdgcn_s_setprio(0);
    }
    if(tt<NT_-1){ writeK(cur^1); loadV(tt+1); }  // K regs die; V loads in flight
    // ---- mask + scale + tile max ----
    const float* mrow = mask + ((long)b*S_ + ((wid*16 + l15)&31))*KV_ + kvbase + tt*KT_;
    float tmx = -3.0e38f;
    #pragma unroll
    for(int kt=0;kt<4;kt++){
      const float4 mk = *(const float4*)(mrow + kt*16 + lq*4);
      sc[kt][0] = sc[kt][0]*SCALE_ + mk.x;
      sc[kt][1] = sc[kt][1]*SCALE_ + mk.y;
      sc[kt][2] = sc[kt][2]*SCALE_ + mk.z;
      sc[kt][3] = sc[kt][3]*SCALE_ + mk.w;
      tmx = fmaxf(tmx, fmaxf(fmaxf(sc[kt][0], sc[kt][1]), fmaxf(sc[kt][2], sc[kt][3])));
    }
    tmx = fmaxf(tmx, __shfl_xor(tmx, 16, 64));
    tmx = fmaxf(tmx, __shfl_xor(tmx, 32, 64));
    // ---- T13 defer-rescale ----
    if(!__all(tmx - m_run <= 8.0f)){
      const float mx  = fmaxf(m_run, tmx);
      const float scl = __expf(m_run - mx);   // first iter: exp(-huge)=0
      #pragma unroll
      for(int rr=0;rr<4;rr++){
        const float sq = __shfl(scl, (lane>>4)*4 + rr, 64);  // scl for q'=lq*4+rr
        #pragma unroll
        for(int ht=0;ht<8;ht++) oc[ht][rr] *= sq;
      }
      l_run *= scl;
      m_run = mx;
    }
    // ---- exp + per-lane partial sum (16 kv values per lane) ----
    float psum = 0.f;
    #pragma unroll
    for(int kt=0;kt<4;kt++)
      #pragma unroll
      for(int e=0;e<4;e++){
        const float p = __expf(sc[kt][e] - m_run);
        sc[kt][e] = p; psum += p;
      }
    l_run += psum;
    // ---- pack P (q=l15, kv=kt*16+lq*4+r) to bf16 pairs ----
    unsigned w_[4][2];
    #pragma unroll
    for(int kt=0;kt<4;kt++){
      w_[kt][0] = pk2(sc[kt][0], sc[kt][1]);
      w_[kt][1] = pk2(sc[kt][2], sc[kt][3]);
    }
    // ---- redistribute P into A-frags: pa[b] covers kv=b*32+lq*8+e ----
    const int src0 = l15 + ((lq&1)<<5);      // source lane group (lq&1)*2
    const int src1 = src0 + 16;              // source lane group (lq&1)*2+1
    unsigned a_[4][4];
    #pragma unroll
    for(int kt=0;kt<4;kt++){
      a_[kt][0] = __shfl(w_[kt][0], src0, 64);
      a_[kt][1] = __shfl(w_[kt][1], src0, 64);
      a_[kt][2] = __shfl(w_[kt][0], src1, 64);
      a_[kt][3] = __shfl(w_[kt][1], src1, 64);
    }
    const bool hiKt = ((lq>>1)&1);           // frag b uses kt=2b+(lq>>1)
    union{ unsigned u[4]; bf16x8 v; } pa0, pa1;
    #pragma unroll
    for(int j=0;j<4;j++){
      pa0.u[j] = hiKt ? a_[1][j] : a_[0][j];
      pa1.u[j] = hiKt ? a_[3][j] : a_[2][j];
    }
    // ---- PV: oc[ht] D[q16][hd16]; lane hd=l15, q=lq*4+r ----
    { const unsigned short* Sv = &lds[cur][1][0];
      __builtin_amdgcn_s_setprio(1);
      #pragma unroll
      for(int ht=0;ht<8;ht++){
        oc[ht] = mf(pa0.v, ld_frag(Sv + swiV(ht*16 + l15,      lq*8)), oc[ht]);
        oc[ht] = mf(pa1.v, ld_frag(Sv + swiV(ht*16 + l15, 32 + lq*8)), oc[ht]);
      }
      __builtin_amdgcn_s_setprio(0);
    }
    // ---- stage next V into other buffer ----
    if(tt<NT_-1) writeV(cur^1);
    __syncthreads();
  }

  // ---- epilogue: write partials ----
  float l_tot = l_run + __shfl_xor(l_run, 16, 64);
  l_tot += __shfl_xor(l_tot, 32, 64);
  if(lane < 16){
    const long base = ((long)bk*NSP + sp)*M_ + wid*16 + lane;
    mbuf[base] = m_run;
    lbuf[base] = l_tot;
  }
  unsigned short* np_ = num + (((long)bk*NSP + sp)*M_ + wid*16)*HD_;
  #pragma unroll
  for(int ht=0;ht<8;ht++)
    #pragma unroll
    for(int rr=0;rr<4;rr++)
      np_[(long)(lq*4+rr)*HD_ + ht*16 + l15] = f2b(oc[ht][rr]);
}

// ---------------- K4: combine split-KV partials ----------------
__global__ __launch_bounds__(128) void k_comb(
    const unsigned short* __restrict__ num, const float* __restrict__ mbuf,
    const float* __restrict__ lbuf, unsigned short* __restrict__ attnb)
{
  const int q = blockIdx.x, kvh = blockIdx.y, b = blockIdx.z, d = threadIdx.x;
  const int bk = b*NKV_ + kvh;
  float M = -3.0e38f;
  #pragma unroll
  for(int c=0;c<NSP;c++) M = fmaxf(M, mbuf[((long)bk*NSP + c)*M_ + q]);
  float den = 0.f, acc = 0.f;
  #pragma unroll
  for(int c=0;c<NSP;c++){
    const long ix = ((long)bk*NSP + c)*M_ + q;
    const float w = __expf(mbuf[ix] - M);
    den += lbuf[ix]*w;
    acc += w * b2f(num[ix*HD_ + d]);
  }
  const int g = q>>5, s = q&31, h = kvh*G_ + g;
  attnb[((long)(b*S_+s))*2048 + h*HD_ + d] = f2b(acc/den);
}

// ---------------- K5: output projection GEMM ----------------
__global__ __launch_bounds__(256) void k_gemm_o(
    const unsigned short* __restrict__ A,
    const float* __restrict__ W,
    float* __restrict__ out)
{
  __shared__ unsigned short As[64][56];
  __shared__ unsigned short Bs[64][56];
  const int n0 = blockIdx.x*64, m0 = blockIdx.y*64;
  const int t = threadIdx.x, lane = t&63, wid = t>>6;
  const int wr = wid>>1, wc = wid&1, l15 = lane&15, lq = lane>>4;
  const int ar = t>>2,  ac = (t&3)*8;
  const int bk = t>>5,  bn = (t&31)*2;
  f32x4 acc[2][2] = {};
  for(int k0 = 0; k0 < 2048; k0 += 32){
    __syncthreads();
    *(uint4*)(&As[ar][ac]) = *(const uint4*)(A + (m0+ar)*2048 + k0 + ac);
    #pragma unroll
    for(int p=0;p<4;p++){
      const int kk = bk + p*8;
      const float2 wv = *(const float2*)(W + (long)(k0+kk)*2048 + n0 + bn);
      Bs[bn  ][kk] = f2b(wv.x);
      Bs[bn+1][kk] = f2b(wv.y);
    }
    __syncthreads();
    const bf16x8 a0 = ld_frag(&As[wr*32      + l15][lq*8]);
    const bf16x8 a1 = ld_frag(&As[wr*32 + 16 + l15][lq*8]);
    const bf16x8 b0 = ld_frag(&Bs[wc*32      + l15][lq*8]);
    const bf16x8 b1 = ld_frag(&Bs[wc*32 + 16 + l15][lq*8]);
    acc[0][0] = mf(a0,b0,acc[0][0]);
    acc[0][1] = mf(a0,b1,acc[0][1]);
    acc[1][0] = mf(a1,b0,acc[1][0]);
    acc[1][1] = mf(a1,b1,acc[1][1]);
  }
  #pragma unroll
  for(int mi=0;mi<2;mi++)
    #pragma unroll
    for(int nj=0;nj<2;nj++){
      const int col = n0 + wc*32 + nj*16 + l15;
      #pragma unroll
      for(int rr=0;rr<4;rr++){
        const int row = m0 + wr*32 + mi*16 + lq*4 + rr;
        out[row*2048 + col] = acc[mi][nj][rr];
      }
    }
}

extern "C" void kernel_launch(void* const* d_in, const int* in_sizes, int n_in,
                              void* d_out, int out_size, void* d_ws, size_t ws_size,
                              hipStream_t stream){
  (void)in_sizes; (void)n_in; (void)out_size; (void)ws_size;
  const float* hs   = (const float*)d_in[0];
  const float* cosb = (const float*)d_in[1];
  const float* sinb = (const float*)d_in[2];
  const float* kc   = (const float*)d_in[3];
  const float* vc   = (const float*)d_in[4];
  const float* mask = (const float*)d_in[5];
  const int*   rp   = (const int*)  d_in[6];
  const float* qw   = (const float*)d_in[7];
  const float* qb   = (const float*)d_in[8];
  const float* kw   = (const float*)d_in[9];
  const float* kb   = (const float*)d_in[10];
  const float* vw   = (const float*)d_in[11];
  const float* vb   = (const float*)d_in[12];
  const float* ow   = (const float*)d_in[13];
  char* ws = (char*)d_ws;
  // ws layout (bytes)
  unsigned short* hsb   = (unsigned short*)(ws + 0);          // 1,048,576
  float*          rawp  = (float*)         (ws + 1048576);    // 5,242,880 (2 K-halves)
  unsigned short* Qb    = (unsigned short*)(ws + 6291456);    // 1,048,576
  float*          KnF   = (float*)         (ws + 7340032);    //   262,144
  float*          VnF   = (float*)         (ws + 7602176);    //   262,144
  unsigned short* attnb = (unsigned short*)(ws + 7864320);    // 1,048,576
  float*          mbuf  = (float*)         (ws + 8912896);    //   262,144
  float*          lbuf  = (float*)         (ws + 9175040);    //   262,144
  unsigned short* num   = (unsigned short*)(ws + 9437184);    // 16,777,216  (end ~26.2 MB)
  float* outp = (float*)d_out;

  k_cvt     <<<dim3(512),        dim3(256),  0, stream>>>(hs, hsb);
  k_gemm_qkv<<<dim3(40,4,2),     dim3(256),  0, stream>>>(hsb, qw,kw,vw, qb,kb,vb, rawp);
  k_rope    <<<dim3(256,20),     dim3(128),  0, stream>>>(rawp, cosb, sinb, Qb, KnF, VnF);
  k_attn    <<<dim3(NSP,2,8),    dim3(1024), 0, stream>>>(Qb, KnF, VnF, kc, vc, mask, rp, num, mbuf, lbuf);
  k_comb    <<<dim3(256,2,8),    dim3(128),  0, stream>>>(num, mbuf, lbuf, attnb);
  k_gemm_o  <<<dim3(32,4),       dim3(256),  0, stream>>>(attnb, ow, outp);
}

// Round 9
// 124.640 us; speedup vs baseline: 2.8434x; 1.2122x over previous
//
#include <hip/hip_runtime.h>
#include <hip/hip_bf16.h>

#define B_    8
#define S_    32
#define H_    2048
#define NH_   16
#define NKV_  2
#define HD_   128
#define KV_   8192
#define G_    8
#define M_    256      /* B*S */
#define NQKV  2560     /* fused proj N: 2048 q | 256 k | 256 v */
#define NSP   16       /* kv splits */
#define KT_   64       /* kv subtile */
#define NT_   8        /* subtiles per block = KV_/NSP/KT_ */
#define SCALE_ 0.08838834764831845f

typedef __bf16 bf16x8 __attribute__((ext_vector_type(8)));
typedef float  f32x4  __attribute__((ext_vector_type(4)));

__device__ __forceinline__ unsigned short f2b(float f){
  unsigned u = __float_as_uint(f);
  u = u + 0x7FFFu + ((u>>16)&1u);           // RNE f32->bf16
  return (unsigned short)(u>>16);
}
__device__ __forceinline__ float b2f(unsigned short h){
  return __uint_as_float(((unsigned)h)<<16);
}
__device__ __forceinline__ unsigned pk2(float a, float b){
  return (unsigned)f2b(a) | ((unsigned)f2b(b)<<16);
}
__device__ __forceinline__ bf16x8 ld_frag(const unsigned short* p){
  union { uint4 u; bf16x8 b; } cv;
  cv.u = *(const uint4*)p;
  return cv.b;
}
__device__ __forceinline__ f32x4 mf(bf16x8 a, bf16x8 b, f32x4 c){
  return __builtin_amdgcn_mfma_f32_16x16x32_bf16(a, b, c, 0, 0, 0);
}
// K tile swizzle: 64 rows x 128 cols (shorts), 16B-group XOR
__device__ __forceinline__ int swiK(int row, int col){
  return row*128 + (col ^ ((((row)&15) ^ ((row>>1)&8)) << 3));
}
// Vt tile swizzle: 128 rows x 64 cols (shorts)
__device__ __forceinline__ int swiV(int row, int col){
  return row*64 + (col ^ (((row)&7) << 3));
}

// ---------------- K0: hidden_states f32 -> bf16 ----------------
__global__ __launch_bounds__(256) void k_cvt(const float* __restrict__ x,
                                             unsigned short* __restrict__ y){
  const int i = (blockIdx.x*256 + threadIdx.x)*4;
  const float4 v = *(const float4*)(x + i);
  ushort4 o; o.x=f2b(v.x); o.y=f2b(v.y); o.z=f2b(v.z); o.w=f2b(v.w);
  *(ushort4*)(y + i) = o;
}

// ---------------- K1: fused QKV projection GEMM, split-K=2 ----------------
__global__ __launch_bounds__(256) void k_gemm_qkv(
    const unsigned short* __restrict__ A,
    const float* __restrict__ qw, const float* __restrict__ kw, const float* __restrict__ vw,
    const float* __restrict__ qbv, const float* __restrict__ kbv, const float* __restrict__ vbv,
    float* __restrict__ rawp)
{
  __shared__ unsigned short As[64][56];
  __shared__ unsigned short Bs[64][56];
  const int n0 = blockIdx.x*64, m0 = blockIdx.y*64, kz = blockIdx.z;
  const float* W; const float* bias; int ldw, wc0;
  if(n0 < 2048)      { W=qw; bias=qbv; ldw=2048; wc0=n0; }
  else if(n0 < 2304) { W=kw; bias=kbv; ldw=256;  wc0=n0-2048; }
  else               { W=vw; bias=vbv; ldw=256;  wc0=n0-2304; }
  const int t = threadIdx.x, lane = t&63, wid = t>>6;
  const int wr = wid>>1, wc = wid&1, l15 = lane&15, lq = lane>>4;
  const int ar = t>>2,  ac = (t&3)*8;
  const int bk = t>>5,  bn = (t&31)*2;
  f32x4 acc[2][2] = {};
  for(int k0 = kz*1024; k0 < kz*1024 + 1024; k0 += 32){
    __syncthreads();
    *(uint4*)(&As[ar][ac]) = *(const uint4*)(A + (m0+ar)*2048 + k0 + ac);
    #pragma unroll
    for(int p=0;p<4;p++){
      const int kk = bk + p*8;
      const float2 wv = *(const float2*)(W + (long)(k0+kk)*ldw + wc0 + bn);
      Bs[bn  ][kk] = f2b(wv.x);
      Bs[bn+1][kk] = f2b(wv.y);
    }
    __syncthreads();
    const bf16x8 a0 = ld_frag(&As[wr*32      + l15][lq*8]);
    const bf16x8 a1 = ld_frag(&As[wr*32 + 16 + l15][lq*8]);
    const bf16x8 b0 = ld_frag(&Bs[wc*32      + l15][lq*8]);
    const bf16x8 b1 = ld_frag(&Bs[wc*32 + 16 + l15][lq*8]);
    acc[0][0] = mf(a0,b0,acc[0][0]);
    acc[0][1] = mf(a0,b1,acc[0][1]);
    acc[1][0] = mf(a1,b0,acc[1][0]);
    acc[1][1] = mf(a1,b1,acc[1][1]);
  }
  float* out = rawp + (long)kz*M_*NQKV;
  #pragma unroll
  for(int mi=0;mi<2;mi++)
    #pragma unroll
    for(int nj=0;nj<2;nj++){
      const int col = n0 + wc*32 + nj*16 + l15;
      const float bv = kz ? 0.f : bias[wc0 + wc*32 + nj*16 + l15];
      #pragma unroll
      for(int rr=0;rr<4;rr++){
        const int row = m0 + wr*32 + mi*16 + lq*4 + rr;
        out[row*NQKV + col] = acc[mi][nj][rr] + bv;
      }
    }
}

// ---------------- K2: sum K-halves + RoPE + pack ----------------
__global__ __launch_bounds__(128) void k_rope(
    const float* __restrict__ rawp, const float* __restrict__ cosb, const float* __restrict__ sinb,
    unsigned short* __restrict__ Qb, float* __restrict__ KnF, float* __restrict__ VnF)
{
  const int r = blockIdx.x, hh = blockIdx.y, d = threadIdx.x;
  const int b = r>>5, s = r&31;
  const float cv = cosb[(b*S_+s)*HD_ + d];
  const float sv = sinb[(b*S_+s)*HD_ + d];
  const int dp = (d<64)? d+64 : d-64;
  #define RAW2(c) (rawp[r*NQKV + (c)] + rawp[(long)M_*NQKV + r*NQKV + (c)])
  if(hh < 16){
    const float x  = RAW2(hh*HD_ + d);
    const float xo = RAW2(hh*HD_ + dp);
    const float y  = x*cv + ((d<64)? -xo : xo)*sv;
    const int kvh = hh>>3, g = hh&7;
    Qb[((long)(b*NKV_+kvh)*M_ + g*S_ + s)*HD_ + d] = f2b(y);
  } else if(hh < 18){
    const int kvh = hh-16;
    const float x  = RAW2(2048 + kvh*HD_ + d);
    const float xo = RAW2(2048 + kvh*HD_ + dp);
    KnF[((long)(b*NKV_+kvh)*S_ + s)*HD_ + d] = x*cv + ((d<64)? -xo : xo)*sv;
  } else {
    const int kvh = hh-18;
    VnF[((long)(b*NKV_+kvh)*S_ + s)*HD_ + d] = RAW2(2304 + kvh*HD_ + d);
  }
  #undef RAW2
}

// ---------------- K3: split-KV attention, T14 schedule, mask in LDS ---------
// grid (sp=16, kvh=2, b=8) = 256 blocks -> 1 block/CU, 16 waves.
// Per iter: [all t+1 loads] -> QK^T -> softmax(mask from LDS) -> PV ->
//           [all t+1 LDS writes] -> single barrier.
__global__ __launch_bounds__(1024, 4) void k_attn(
    const unsigned short* __restrict__ Qb,
    const float* __restrict__ KnF, const float* __restrict__ VnF,
    const float* __restrict__ kc, const float* __restrict__ vc,
    const float* __restrict__ mask, const int* __restrict__ rpp,
    unsigned short* __restrict__ num, float* __restrict__ mbuf, float* __restrict__ lbuf)
{
  __shared__ __align__(16) unsigned short lds[2][2][KT_*128]; // [buf][K|Vt] 64KB
  __shared__ __align__(16) float mlds[2][32][68];             // mask tiles 17.4KB
  const int sp = blockIdx.x, kvh = blockIdx.y, b = blockIdx.z;
  const int bk = b*NKV_ + kvh;
  const int rp = *rpp;
  const int t = threadIdx.x, lane = t&63, wid = t>>6;   // wid 0..15
  const int l15 = lane&15, lq = lane>>4;
  const int kvbase = sp*(KV_/NSP);
  // staging mappings (1024 threads)
  const int krow = t>>4, kc0 = (t&15)*8;  // K: 64 rows x 16 col-eighths (8 f32)
  const int vhd  = t&127, vkq = t>>7;     // V: 128 hd cols x 8 kv-eighths (8 rows)
  const int mrw  = t>>5,  mcl = (t&31)*2; // mask: 32 rows x 32 col-pairs

  // Q fragments (wave's 16 q rows; lane: q=l15, k=ks*32+lq*8)
  bf16x8 qf[4];
  { const unsigned short* qp = Qb + ((long)bk*M_ + wid*16 + l15)*HD_;
    #pragma unroll
    for(int ks=0;ks<4;ks++) qf[ks] = ld_frag(qp + ks*32 + lq*8); }

  float4 vK4[2];
  float  vV[8];
  float2 vM;

  auto loadK = [&](int tt){
    const int kvr = kvbase + tt*KT_ + krow;
    const float* kp = (kvr>=rp && kvr<rp+S_)
        ? (KnF + ((long)bk*S_ + (kvr-rp))*HD_ + kc0)
        : (kc  + ((long)bk*KV_ + kvr)*HD_ + kc0);
    vK4[0] = *(const float4*)(kp);
    vK4[1] = *(const float4*)(kp + 4);
  };
  auto loadV = [&](int tt){
    #pragma unroll
    for(int m=0;m<8;m++){
      const int kvr = kvbase + tt*KT_ + vkq*8 + m;   // wave-uniform row
      const float* vp = (kvr>=rp && kvr<rp+S_)
          ? (VnF + ((long)bk*S_ + (kvr-rp))*HD_)
          : (vc  + ((long)bk*KV_ + kvr)*HD_);
      vV[m] = vp[vhd];
    }
  };
  auto loadM = [&](int tt){
    vM = *(const float2*)(mask + ((long)b*S_ + mrw)*KV_ + kvbase + tt*KT_ + mcl);
  };
  auto writeK = [&](int bb){
    unsigned short* Sb = &lds[bb][0][0];
    uint4 w4;
    w4.x = pk2(vK4[0].x, vK4[0].y);  w4.y = pk2(vK4[0].z, vK4[0].w);
    w4.z = pk2(vK4[1].x, vK4[1].y);  w4.w = pk2(vK4[1].z, vK4[1].w);
    *(uint4*)(Sb + swiK(krow, kc0)) = w4;
  };
  auto writeV = [&](int bb){
    unsigned short* Sb = &lds[bb][1][0];
    uint4 w4;
    w4.x = pk2(vV[0], vV[1]);   w4.y = pk2(vV[2], vV[3]);
    w4.z = pk2(vV[4], vV[5]);   w4.w = pk2(vV[6], vV[7]);
    *(uint4*)(Sb + swiV(vhd, vkq*8)) = w4;
  };
  auto writeM = [&](int bb){
    *(float2*)(&mlds[bb][mrw][mcl]) = vM;
  };

  // prologue: stage subtile 0 into buf 0
  loadK(0); loadV(0); loadM(0);
  writeK(0); writeV(0); writeM(0);
  __syncthreads();

  f32x4 oc[8] = {};
  float m_run = -3.0e38f, l_run = 0.f;
  const int mq = (wid*16 + l15) & 31;       // this lane's mask row

  for(int tt=0; tt<NT_; tt++){
    const int cur = tt&1;
    // ---- issue ALL t+1 global loads first (latency spans whole iteration) ----
    if(tt<NT_-1){ loadK(tt+1); loadV(tt+1); loadM(tt+1); }
    // ---- QK^T: sc[kt] = D[kv16][q16]; lane q=l15, kv=kt*16+lq*4+r ----
    f32x4 sc[4] = {};
    { const unsigned short* Sk = &lds[cur][0][0];
      __builtin_amdgcn_s_setprio(1);
      #pragma unroll
      for(int ks=0;ks<4;ks++){
        #pragma unroll
        for(int kt=0;kt<4;kt++)
          sc[kt] = mf(ld_frag(Sk + swiK(kt*16 + l15, ks*32 + lq*8)), qf[ks], sc[kt]);
      }
      __builtin_amdgcn_s_setprio(0);
    }
    // ---- mask (from LDS) + scale + tile max ----
    float tmx = -3.0e38f;
    #pragma unroll
    for(int kt=0;kt<4;kt++){
      const float4 mk = *(const float4*)(&mlds[cur][mq][kt*16 + lq*4]);
      sc[kt][0] = sc[kt][0]*SCALE_ + mk.x;
      sc[kt][1] = sc[kt][1]*SCALE_ + mk.y;
      sc[kt][2] = sc[kt][2]*SCALE_ + mk.z;
      sc[kt][3] = sc[kt][3]*SCALE_ + mk.w;
      tmx = fmaxf(tmx, fmaxf(fmaxf(sc[kt][0], sc[kt][1]), fmaxf(sc[kt][2], sc[kt][3])));
    }
    tmx = fmaxf(tmx, __shfl_xor(tmx, 16, 64));
    tmx = fmaxf(tmx, __shfl_xor(tmx, 32, 64));
    // ---- T13 defer-rescale ----
    if(!__all(tmx - m_run <= 8.0f)){
      const float mx  = fmaxf(m_run, tmx);
      const float scl = __expf(m_run - mx);   // first iter: exp(-huge)=0
      #pragma unroll
      for(int rr=0;rr<4;rr++){
        const float sq = __shfl(scl, lq*4 + rr, 64);   // scl for q'=lq*4+rr
        #pragma unroll
        for(int ht=0;ht<8;ht++) oc[ht][rr] *= sq;
      }
      l_run *= scl;
      m_run = mx;
    }
    // ---- exp + per-lane partial sum (16 kv values per lane) ----
    float psum = 0.f;
    #pragma unroll
    for(int kt=0;kt<4;kt++)
      #pragma unroll
      for(int e=0;e<4;e++){
        const float p = __expf(sc[kt][e] - m_run);
        sc[kt][e] = p; psum += p;
      }
    l_run += psum;
    // ---- pack P (q=l15, kv=kt*16+lq*4+r) to bf16 pairs ----
    unsigned w_[4][2];
    #pragma unroll
    for(int kt=0;kt<4;kt++){
      w_[kt][0] = pk2(sc[kt][0], sc[kt][1]);
      w_[kt][1] = pk2(sc[kt][2], sc[kt][3]);
    }
    // ---- redistribute P into A-frags: pa[b] covers kv=b*32+lq*8+e ----
    const int src0 = l15 + ((lq&1)<<5);
    const int src1 = src0 + 16;
    unsigned a_[4][4];
    #pragma unroll
    for(int kt=0;kt<4;kt++){
      a_[kt][0] = __shfl(w_[kt][0], src0, 64);
      a_[kt][1] = __shfl(w_[kt][1], src0, 64);
      a_[kt][2] = __shfl(w_[kt][0], src1, 64);
      a_[kt][3] = __shfl(w_[kt][1], src1, 64);
    }
    const bool hiKt = ((lq>>1)&1);
    union{ unsigned u[4]; bf16x8 v; } pa0, pa1;
    #pragma unroll
    for(int j=0;j<4;j++){
      pa0.u[j] = hiKt ? a_[1][j] : a_[0][j];
      pa1.u[j] = hiKt ? a_[3][j] : a_[2][j];
    }
    // ---- PV: oc[ht] D[q16][hd16]; lane hd=l15, q=lq*4+r ----
    { const unsigned short* Sv = &lds[cur][1][0];
      __builtin_amdgcn_s_setprio(1);
      #pragma unroll
      for(int ht=0;ht<8;ht++){
        oc[ht] = mf(pa0.v, ld_frag(Sv + swiV(ht*16 + l15,      lq*8)), oc[ht]);
        oc[ht] = mf(pa1.v, ld_frag(Sv + swiV(ht*16 + l15, 32 + lq*8)), oc[ht]);
      }
      __builtin_amdgcn_s_setprio(0);
    }
    // ---- write ALL t+1 LDS tiles (vmcnt drained here, latency already covered) ----
    if(tt<NT_-1){ writeK(cur^1); writeV(cur^1); writeM(cur^1); }
    __syncthreads();
  }

  // ---- epilogue: write partials ----
  float l_tot = l_run + __shfl_xor(l_run, 16, 64);
  l_tot += __shfl_xor(l_tot, 32, 64);
  if(lane < 16){
    const long base = ((long)bk*NSP + sp)*M_ + wid*16 + lane;
    mbuf[base] = m_run;
    lbuf[base] = l_tot;
  }
  unsigned short* np_ = num + (((long)bk*NSP + sp)*M_ + wid*16)*HD_;
  #pragma unroll
  for(int ht=0;ht<8;ht++)
    #pragma unroll
    for(int rr=0;rr<4;rr++)
      np_[(long)(lq*4+rr)*HD_ + ht*16 + l15] = f2b(oc[ht][rr]);
}

// ---------------- K4: combine split-KV partials ----------------
__global__ __launch_bounds__(128) void k_comb(
    const unsigned short* __restrict__ num, const float* __restrict__ mbuf,
    const float* __restrict__ lbuf, unsigned short* __restrict__ attnb)
{
  const int q = blockIdx.x, kvh = blockIdx.y, b = blockIdx.z, d = threadIdx.x;
  const int bk = b*NKV_ + kvh;
  float M = -3.0e38f;
  #pragma unroll
  for(int c=0;c<NSP;c++) M = fmaxf(M, mbuf[((long)bk*NSP + c)*M_ + q]);
  float den = 0.f, acc = 0.f;
  #pragma unroll
  for(int c=0;c<NSP;c++){
    const long ix = ((long)bk*NSP + c)*M_ + q;
    const float w = __expf(mbuf[ix] - M);
    den += lbuf[ix]*w;
    acc += w * b2f(num[ix*HD_ + d]);
  }
  const int g = q>>5, s = q&31, h = kvh*G_ + g;
  attnb[((long)(b*S_+s))*2048 + h*HD_ + d] = f2b(acc/den);
}

// ---------------- K5: output projection GEMM, split-K=2 ----------------
__global__ __launch_bounds__(256) void k_gemm_o(
    const unsigned short* __restrict__ A,
    const float* __restrict__ W,
    float* __restrict__ owsp)
{
  __shared__ unsigned short As[64][56];
  __shared__ unsigned short Bs[64][56];
  const int n0 = blockIdx.x*64, m0 = blockIdx.y*64, kz = blockIdx.z;
  const int t = threadIdx.x, lane = t&63, wid = t>>6;
  const int wr = wid>>1, wc = wid&1, l15 = lane&15, lq = lane>>4;
  const int ar = t>>2,  ac = (t&3)*8;
  const int bk = t>>5,  bn = (t&31)*2;
  f32x4 acc[2][2] = {};
  for(int k0 = kz*1024; k0 < kz*1024 + 1024; k0 += 32){
    __syncthreads();
    *(uint4*)(&As[ar][ac]) = *(const uint4*)(A + (m0+ar)*2048 + k0 + ac);
    #pragma unroll
    for(int p=0;p<4;p++){
      const int kk = bk + p*8;
      const float2 wv = *(const float2*)(W + (long)(k0+kk)*2048 + n0 + bn);
      Bs[bn  ][kk] = f2b(wv.x);
      Bs[bn+1][kk] = f2b(wv.y);
    }
    __syncthreads();
    const bf16x8 a0 = ld_frag(&As[wr*32      + l15][lq*8]);
    const bf16x8 a1 = ld_frag(&As[wr*32 + 16 + l15][lq*8]);
    const bf16x8 b0 = ld_frag(&Bs[wc*32      + l15][lq*8]);
    const bf16x8 b1 = ld_frag(&Bs[wc*32 + 16 + l15][lq*8]);
    acc[0][0] = mf(a0,b0,acc[0][0]);
    acc[0][1] = mf(a0,b1,acc[0][1]);
    acc[1][0] = mf(a1,b0,acc[1][0]);
    acc[1][1] = mf(a1,b1,acc[1][1]);
  }
  float* out = owsp + (long)kz*M_*2048;
  #pragma unroll
  for(int mi=0;mi<2;mi++)
    #pragma unroll
    for(int nj=0;nj<2;nj++){
      const int col = n0 + wc*32 + nj*16 + l15;
      #pragma unroll
      for(int rr=0;rr<4;rr++){
        const int row = m0 + wr*32 + mi*16 + lq*4 + rr;
        out[row*2048 + col] = acc[mi][nj][rr];
      }
    }
}

// ---------------- K6: fold the two O K-halves ----------------
__global__ __launch_bounds__(256) void k_ored(const float* __restrict__ a,
                                              float* __restrict__ out){
  const int i = (blockIdx.x*256 + threadIdx.x)*4;
  const float4 x = *(const float4*)(a + i);
  const float4 y = *(const float4*)(a + (long)M_*2048 + i);
  float4 o; o.x=x.x+y.x; o.y=x.y+y.y; o.z=x.z+y.z; o.w=x.w+y.w;
  *(float4*)(out + i) = o;
}

extern "C" void kernel_launch(void* const* d_in, const int* in_sizes, int n_in,
                              void* d_out, int out_size, void* d_ws, size_t ws_size,
                              hipStream_t stream){
  (void)in_sizes; (void)n_in; (void)out_size; (void)ws_size;
  const float* hs   = (const float*)d_in[0];
  const float* cosb = (const float*)d_in[1];
  const float* sinb = (const float*)d_in[2];
  const float* kc   = (const float*)d_in[3];
  const float* vc   = (const float*)d_in[4];
  const float* mask = (const float*)d_in[5];
  const int*   rp   = (const int*)  d_in[6];
  const float* qw   = (const float*)d_in[7];
  const float* qb   = (const float*)d_in[8];
  const float* kw   = (const float*)d_in[9];
  const float* kb   = (const float*)d_in[10];
  const float* vw   = (const float*)d_in[11];
  const float* vb   = (const float*)d_in[12];
  const float* ow   = (const float*)d_in[13];
  char* ws = (char*)d_ws;
  // ws layout (bytes)
  unsigned short* hsb   = (unsigned short*)(ws + 0);          // 1,048,576
  float*          rawp  = (float*)         (ws + 1048576);    // 5,242,880 (2 K-halves)
  unsigned short* Qb    = (unsigned short*)(ws + 6291456);    // 1,048,576
  float*          KnF   = (float*)         (ws + 7340032);    //   262,144
  float*          VnF   = (float*)         (ws + 7602176);    //   262,144
  unsigned short* attnb = (unsigned short*)(ws + 7864320);    // 1,048,576
  float*          mbuf  = (float*)         (ws + 8912896);    //   262,144
  float*          lbuf  = (float*)         (ws + 9175040);    //   262,144
  unsigned short* num   = (unsigned short*)(ws + 9437184);    // 16,777,216
  float*          owsp  = (float*)         (ws + 26214400);   //  4,194,304 (end ~30.4 MB)
  float* outp = (float*)d_out;

  k_cvt     <<<dim3(512),        dim3(256),  0, stream>>>(hs, hsb);
  k_gemm_qkv<<<dim3(40,4,2),     dim3(256),  0, stream>>>(hsb, qw,kw,vw, qb,kb,vb, rawp);
  k_rope    <<<dim3(256,20),     dim3(128),  0, stream>>>(rawp, cosb, sinb, Qb, KnF, VnF);
  k_attn    <<<dim3(NSP,2,8),    dim3(1024), 0, stream>>>(Qb, KnF, VnF, kc, vc, mask, rp, num, mbuf, lbuf);
  k_comb    <<<dim3(256,2,8),    dim3(128),  0, stream>>>(num, mbuf, lbuf, attnb);
  k_gemm_o  <<<dim3(32,4,2),     dim3(256),  0, stream>>>(attnb, ow, owsp);
  k_ored    <<<dim3(512),        dim3(256),  0, stream>>>(owsp, outp);
}